// Round 1
// baseline (857.512 us; speedup 1.0000x reference)
//
#include <hip/hip_runtime.h>
#include <math.h>

#define N_NODES 100000
#define N_EDGES 1600000
#define FEAT 128

// ---------------------------------------------------------------- utilities
__global__ __launch_bounds__(256) void zero_i32(int* p, int n) {
    int i = blockIdx.x * 256 + threadIdx.x;
    if (i < n) p[i] = 0;
}

__global__ __launch_bounds__(256) void count_deg(const int* __restrict__ dst,
                                                 int* __restrict__ cnt) {
    int e = blockIdx.x * 256 + threadIdx.x;
    if (e < N_EDGES) atomicAdd(&cnt[dst[e]], 1);
}

// inclusive scan of 1024-elem chunks; out = rowptr+1
__global__ __launch_bounds__(1024) void scan_chunks(const int* __restrict__ in,
                                                    int* __restrict__ out,
                                                    int* __restrict__ bsums) {
    __shared__ int s[1024];
    int g = blockIdx.x * 1024 + threadIdx.x;
    int v = (g < N_NODES) ? in[g] : 0;
    s[threadIdx.x] = v;
    __syncthreads();
    for (int off = 1; off < 1024; off <<= 1) {
        int t = (threadIdx.x >= off) ? s[threadIdx.x - off] : 0;
        __syncthreads();
        s[threadIdx.x] += t;
        __syncthreads();
    }
    if (g < N_NODES) out[g] = s[threadIdx.x];
    if (threadIdx.x == 1023) bsums[blockIdx.x] = s[1023];
}

__global__ __launch_bounds__(128) void scan_totals(int* bsums, int n) {
    __shared__ int s[128];
    int t = threadIdx.x;
    s[t] = (t < n) ? bsums[t] : 0;
    __syncthreads();
    if (t == 0) {
        int run = 0;
        for (int i = 0; i < n; ++i) { int v = s[i]; s[i] = run; run += v; }
    }
    __syncthreads();
    if (t < n) bsums[t] = s[t];
}

// rowptr[1+i] += offset; rowptr[0] = 0; cursor = 0
__global__ __launch_bounds__(1024) void finish_scan(int* __restrict__ rowptr,
                                                    const int* __restrict__ bsums,
                                                    int* __restrict__ cursor) {
    int g = blockIdx.x * 1024 + threadIdx.x;
    if (g < N_NODES) {
        rowptr[1 + g] += bsums[blockIdx.x];
        cursor[g] = 0;
    }
    if (g == 0) rowptr[0] = 0;
}

__global__ __launch_bounds__(256) void fill_csr(const int* __restrict__ src,
                                                const int* __restrict__ dst,
                                                const int* __restrict__ rowptr,
                                                int* __restrict__ cursor,
                                                int* __restrict__ esrc) {
    int e = blockIdx.x * 256 + threadIdx.x;
    if (e < N_EDGES) {
        int d = dst[e];
        int p = rowptr[d] + atomicAdd(&cursor[d], 1);
        esrc[p] = src[e];
    }
}

// ---------------------------------------------------------------- aggregation
// MODE: 0=max (0 if deg==0), 1=sum, 2=mean
// out[n] = (1+eps)*h[n] + agg(h[src] over incoming edges)
template <int MODE>
__global__ __launch_bounds__(256) void agg_kernel(const float* __restrict__ h,
                                                  const int* __restrict__ rowptr,
                                                  const int* __restrict__ esrc,
                                                  const float* __restrict__ eps,
                                                  int ei,
                                                  float* __restrict__ out) {
    int node = (int)((blockIdx.x * 256 + threadIdx.x) >> 6);
    int lane = threadIdx.x & 63;
    if (node >= N_NODES) return;
    int beg = rowptr[node], end = rowptr[node + 1];

    float ax = (MODE == 0) ? -INFINITY : 0.f;
    float ay = ax;

    int e = beg;
    for (; e + 4 <= end; e += 4) {
        int s0 = esrc[e + 0], s1 = esrc[e + 1], s2 = esrc[e + 2], s3 = esrc[e + 3];
        float2 v0 = *(const float2*)(h + (size_t)s0 * FEAT + 2 * lane);
        float2 v1 = *(const float2*)(h + (size_t)s1 * FEAT + 2 * lane);
        float2 v2 = *(const float2*)(h + (size_t)s2 * FEAT + 2 * lane);
        float2 v3 = *(const float2*)(h + (size_t)s3 * FEAT + 2 * lane);
        if (MODE == 0) {
            ax = fmaxf(ax, fmaxf(fmaxf(v0.x, v1.x), fmaxf(v2.x, v3.x)));
            ay = fmaxf(ay, fmaxf(fmaxf(v0.y, v1.y), fmaxf(v2.y, v3.y)));
        } else {
            ax += (v0.x + v1.x) + (v2.x + v3.x);
            ay += (v0.y + v1.y) + (v2.y + v3.y);
        }
    }
    for (; e < end; ++e) {
        int s0 = esrc[e];
        float2 v0 = *(const float2*)(h + (size_t)s0 * FEAT + 2 * lane);
        if (MODE == 0) { ax = fmaxf(ax, v0.x); ay = fmaxf(ay, v0.y); }
        else           { ax += v0.x; ay += v0.y; }
    }

    int deg = end - beg;
    if (MODE == 0 && deg == 0) { ax = 0.f; ay = 0.f; }
    if (MODE == 2) {
        float inv = 1.f / (float)(deg > 1 ? deg : 1);
        ax *= inv; ay *= inv;
    }
    float2 self = *(const float2*)(h + (size_t)node * FEAT + 2 * lane);
    float sc = 1.f + eps[ei];
    float2 o = make_float2(fmaf(sc, self.x, ax), fmaf(sc, self.y, ay));
    *(float2*)(out + (size_t)node * FEAT + 2 * lane) = o;
}

// ---------------------------------------------------------------- GEMM (f32)
// Y[M][BN] = relu?(X[M][128] @ W[128][BN] + B[BN]);  BM=128, BK=32
template <int BN, bool RELU>
__global__ __launch_bounds__(256) void gemm_kernel(const float* __restrict__ X,
                                                   const float* __restrict__ W,
                                                   const float* __restrict__ Bv,
                                                   float* __restrict__ Y) {
    constexpr int BM = 128, BK = 32;
    constexpr int TN = BN / 16;  // 8 (BN=128) or 4 (BN=64)
    __shared__ float xT[BK][BM + 4];
    __shared__ float ws[BK][BN];

    int t = threadIdx.x;
    int tx = t & 15, ty = t >> 4;
    int rowBase = blockIdx.x * BM;

    float acc[8][TN];
#pragma unroll
    for (int i = 0; i < 8; ++i)
#pragma unroll
        for (int n = 0; n < TN; ++n) acc[i][n] = 0.f;

    int lr = t >> 3;         // 0..31
    int lk = (t & 7) * 4;    // 0..28

    for (int kt = 0; kt < 128; kt += BK) {
        // stage X tile transposed: xT[k][row]
#pragma unroll
        for (int j = 0; j < 4; ++j) {
            int r = lr + 32 * j;
            int grow = rowBase + r;
            float4 v = make_float4(0.f, 0.f, 0.f, 0.f);
            if (grow < N_NODES)
                v = *(const float4*)(X + (size_t)grow * 128 + kt + lk);
            xT[lk + 0][r] = v.x;
            xT[lk + 1][r] = v.y;
            xT[lk + 2][r] = v.z;
            xT[lk + 3][r] = v.w;
        }
        // stage W tile: ws[k][c]
        constexpr int NF4 = (BK * BN) / (256 * 4);
#pragma unroll
        for (int j = 0; j < NF4; ++j) {
            int idx = (t + 256 * j) * 4;
            int kk = idx / BN, cc = idx % BN;
            float4 v = *(const float4*)(W + (size_t)(kt + kk) * BN + cc);
            *(float4*)&ws[kk][cc] = v;
        }
        __syncthreads();

#pragma unroll
        for (int k = 0; k < BK; ++k) {
            float4 a0 = *(const float4*)&xT[k][ty * 8];
            float4 a1 = *(const float4*)&xT[k][ty * 8 + 4];
            float av[8] = {a0.x, a0.y, a0.z, a0.w, a1.x, a1.y, a1.z, a1.w};
            float bv[TN];
            if (TN == 8) {
                float4 b0 = *(const float4*)&ws[k][tx * 8];
                float4 b1 = *(const float4*)&ws[k][tx * 8 + 4];
                bv[0] = b0.x; bv[1] = b0.y; bv[2] = b0.z; bv[3] = b0.w;
                bv[4] = b1.x; bv[5] = b1.y; bv[6] = b1.z; bv[7] = b1.w;
            } else {
                float4 b0 = *(const float4*)&ws[k][tx * 4];
                bv[0] = b0.x; bv[1] = b0.y; bv[2] = b0.z; bv[3] = b0.w;
            }
#pragma unroll
            for (int i = 0; i < 8; ++i)
#pragma unroll
                for (int n = 0; n < TN; ++n)
                    acc[i][n] = fmaf(av[i], bv[n], acc[i][n]);
        }
        __syncthreads();
    }

    int colBase = tx * TN;
    float bias[TN];
#pragma unroll
    for (int n = 0; n < TN; ++n) bias[n] = Bv[colBase + n];

#pragma unroll
    for (int i = 0; i < 8; ++i) {
        int row = rowBase + ty * 8 + i;
        if (row >= N_NODES) continue;
        float o[TN];
#pragma unroll
        for (int n = 0; n < TN; ++n) {
            float v = acc[i][n] + bias[n];
            o[n] = RELU ? fmaxf(v, 0.f) : v;
        }
        float* yp = Y + (size_t)row * BN + colBase;
        *(float4*)yp = make_float4(o[0], o[1], o[2], o[3]);
        if (TN == 8)
            *(float4*)(yp + 4) = make_float4(o[4], o[5], o[6], o[7]);
    }
}

// ---------------------------------------------------------------- launch
extern "C" void kernel_launch(void* const* d_in, const int* in_sizes, int n_in,
                              void* d_out, int out_size, void* d_ws, size_t ws_size,
                              hipStream_t stream) {
    const float* feat = (const float*)d_in[0];
    const int*   src  = (const int*)d_in[1];
    const int*   dst  = (const int*)d_in[2];
    const float* W1   = (const float*)d_in[3];
    const float* b1   = (const float*)d_in[4];
    const float* W2a  = (const float*)d_in[5];
    const float* b2a  = (const float*)d_in[6];
    const float* W2b  = (const float*)d_in[7];
    const float* b2b  = (const float*)d_in[8];
    const float* W3   = (const float*)d_in[9];
    const float* b3   = (const float*)d_in[10];
    const float* eps  = (const float*)d_in[11];

    float* hA = (float*)d_ws;
    float* hB = hA + (size_t)N_NODES * FEAT;
    int* rowptr = (int*)(hB + (size_t)N_NODES * FEAT);
    int* cursor = rowptr + (N_NODES + 1);
    int* esrc   = cursor + N_NODES;
    int* bsums  = esrc + N_EDGES;

    const int NCHUNK = (N_NODES + 1023) / 1024;  // 98

    // --- build CSR (dst-sorted incoming edges)
    zero_i32<<<(N_NODES + 255) / 256, 256, 0, stream>>>(cursor, N_NODES);
    count_deg<<<(N_EDGES + 255) / 256, 256, 0, stream>>>(dst, cursor);
    scan_chunks<<<NCHUNK, 1024, 0, stream>>>(cursor, rowptr + 1, bsums);
    scan_totals<<<1, 128, 0, stream>>>(bsums, NCHUNK);
    finish_scan<<<NCHUNK, 1024, 0, stream>>>(rowptr, bsums, cursor);
    fill_csr<<<(N_EDGES + 255) / 256, 256, 0, stream>>>(src, dst, rowptr, cursor, esrc);

    const int AGG_GRID = (N_NODES * 64 + 255) / 256;  // 1 wave per node
    const int GEMM_GRID = (N_NODES + 127) / 128;

    // layer 0: max agg + W1 + relu
    agg_kernel<0><<<AGG_GRID, 256, 0, stream>>>(feat, rowptr, esrc, eps, 0, hB);
    gemm_kernel<128, true><<<GEMM_GRID, 256, 0, stream>>>(hB, W1, b1, hA);
    // layer 1: sum agg + W2a + relu
    agg_kernel<1><<<AGG_GRID, 256, 0, stream>>>(hA, rowptr, esrc, eps, 1, hB);
    gemm_kernel<128, true><<<GEMM_GRID, 256, 0, stream>>>(hB, W2a, b2a, hA);
    // layer 2: sum agg + W2b + relu
    agg_kernel<1><<<AGG_GRID, 256, 0, stream>>>(hA, rowptr, esrc, eps, 2, hB);
    gemm_kernel<128, true><<<GEMM_GRID, 256, 0, stream>>>(hB, W2b, b2b, hA);
    // layer 3: mean agg + W3 (no relu)
    agg_kernel<2><<<AGG_GRID, 256, 0, stream>>>(hA, rowptr, esrc, eps, 3, hB);
    gemm_kernel<64, false><<<GEMM_GRID, 256, 0, stream>>>(hB, W3, b3, (float*)d_out);
}

// Round 3
// 565.376 us; speedup vs baseline: 1.5167x; 1.5167x over previous
//
#include <hip/hip_runtime.h>
#include <math.h>

#define N_NODES 100000
#define N_EDGES 1600000
#define FEAT 128

typedef __attribute__((ext_vector_type(8))) _Float16 half8;
typedef __attribute__((ext_vector_type(4))) float floatx4;

__device__ inline float2 h2f2(unsigned int u) {
    union { unsigned int u; _Float16 h[2]; } x; x.u = u;
    return make_float2((float)x.h[0], (float)x.h[1]);
}
__device__ inline unsigned int f2h2(float a, float b) {
    union { unsigned int u; _Float16 h[2]; } x;
    x.h[0] = (_Float16)a; x.h[1] = (_Float16)b; return x.u;
}

// ---------------------------------------------------------------- utilities
__global__ __launch_bounds__(256) void zero_i32(int* p, int n) {
    int i = blockIdx.x * 256 + threadIdx.x;
    if (i < n) p[i] = 0;
}

__global__ __launch_bounds__(256) void count_deg(const int* __restrict__ dst,
                                                 int* __restrict__ cnt) {
    int e = blockIdx.x * 256 + threadIdx.x;
    if (e < N_EDGES) atomicAdd(&cnt[dst[e]], 1);
}

__global__ __launch_bounds__(1024) void scan_chunks(const int* __restrict__ in,
                                                    int* __restrict__ out,
                                                    int* __restrict__ bsums) {
    __shared__ int s[1024];
    int g = blockIdx.x * 1024 + threadIdx.x;
    int v = (g < N_NODES) ? in[g] : 0;
    s[threadIdx.x] = v;
    __syncthreads();
    for (int off = 1; off < 1024; off <<= 1) {
        int t = (threadIdx.x >= off) ? s[threadIdx.x - off] : 0;
        __syncthreads();
        s[threadIdx.x] += t;
        __syncthreads();
    }
    if (g < N_NODES) out[g] = s[threadIdx.x];
    if (threadIdx.x == 1023) bsums[blockIdx.x] = s[1023];
}

__global__ __launch_bounds__(128) void scan_totals(int* bsums, int n) {
    __shared__ int s[128];
    int t = threadIdx.x;
    s[t] = (t < n) ? bsums[t] : 0;
    __syncthreads();
    if (t == 0) {
        int run = 0;
        for (int i = 0; i < n; ++i) { int v = s[i]; s[i] = run; run += v; }
    }
    __syncthreads();
    if (t < n) bsums[t] = s[t];
}

__global__ __launch_bounds__(1024) void finish_scan(int* __restrict__ rowptr,
                                                    const int* __restrict__ bsums,
                                                    int* __restrict__ cursor) {
    int g = blockIdx.x * 1024 + threadIdx.x;
    if (g < N_NODES) {
        rowptr[1 + g] += bsums[blockIdx.x];
        cursor[g] = 0;
    }
    if (g == 0) rowptr[0] = 0;
}

__global__ __launch_bounds__(256) void fill_csr(const int* __restrict__ src,
                                                const int* __restrict__ dst,
                                                const int* __restrict__ rowptr,
                                                int* __restrict__ cursor,
                                                int* __restrict__ esrc) {
    int e = blockIdx.x * 256 + threadIdx.x;
    if (e < N_EDGES) {
        int d = dst[e];
        int p = rowptr[d] + atomicAdd(&cursor[d], 1);
        esrc[p] = src[e];
    }
}

// ---------------------------------------------------------------- conversions
__global__ __launch_bounds__(256) void f32_to_f16_vec(const float* __restrict__ in,
                                                      _Float16* __restrict__ out,
                                                      int n4) {
    int i = blockIdx.x * 256 + threadIdx.x;
    int stride = gridDim.x * 256;
    for (; i < n4; i += stride) {
        float4 v = ((const float4*)in)[i];
        union { uint2 u; _Float16 h[4]; } p;
        p.h[0] = (_Float16)v.x; p.h[1] = (_Float16)v.y;
        p.h[2] = (_Float16)v.z; p.h[3] = (_Float16)v.w;
        *(uint2*)(out + 4 * (size_t)i) = p.u;
    }
}

// W f32 [K][N] -> WT f16 [N][K]
__global__ __launch_bounds__(256) void wprep(const float* __restrict__ W,
                                             _Float16* __restrict__ WT,
                                             int K, int N) {
    int idx = blockIdx.x * 256 + threadIdx.x;
    if (idx < K * N) {
        int n = idx / K, k = idx % K;
        WT[idx] = (_Float16)W[k * N + n];
    }
}

// ---------------------------------------------------------------- aggregation
// MODE: 0=max (0 if deg==0), 1=sum, 2=mean ; h, out are f16 [N][128]
template <int MODE>
__global__ __launch_bounds__(256) void agg_kernel(const _Float16* __restrict__ h,
                                                  const int* __restrict__ rowptr,
                                                  const int* __restrict__ esrc,
                                                  const float* __restrict__ eps,
                                                  int ei,
                                                  _Float16* __restrict__ out) {
    int node = (int)((blockIdx.x * 256 + threadIdx.x) >> 6);
    int lane = threadIdx.x & 63;
    if (node >= N_NODES) return;
    int beg = rowptr[node], end = rowptr[node + 1];

    float ax = (MODE == 0) ? -INFINITY : 0.f;
    float ay = ax;

    int e = beg;
    for (; e + 4 <= end; e += 4) {
        int s0 = esrc[e + 0], s1 = esrc[e + 1], s2 = esrc[e + 2], s3 = esrc[e + 3];
        unsigned int u0 = *(const unsigned int*)(h + (size_t)s0 * FEAT + 2 * lane);
        unsigned int u1 = *(const unsigned int*)(h + (size_t)s1 * FEAT + 2 * lane);
        unsigned int u2 = *(const unsigned int*)(h + (size_t)s2 * FEAT + 2 * lane);
        unsigned int u3 = *(const unsigned int*)(h + (size_t)s3 * FEAT + 2 * lane);
        float2 v0 = h2f2(u0), v1 = h2f2(u1), v2 = h2f2(u2), v3 = h2f2(u3);
        if (MODE == 0) {
            ax = fmaxf(ax, fmaxf(fmaxf(v0.x, v1.x), fmaxf(v2.x, v3.x)));
            ay = fmaxf(ay, fmaxf(fmaxf(v0.y, v1.y), fmaxf(v2.y, v3.y)));
        } else {
            ax += (v0.x + v1.x) + (v2.x + v3.x);
            ay += (v0.y + v1.y) + (v2.y + v3.y);
        }
    }
    for (; e < end; ++e) {
        int s0 = esrc[e];
        float2 v0 = h2f2(*(const unsigned int*)(h + (size_t)s0 * FEAT + 2 * lane));
        if (MODE == 0) { ax = fmaxf(ax, v0.x); ay = fmaxf(ay, v0.y); }
        else           { ax += v0.x; ay += v0.y; }
    }

    int deg = end - beg;
    if (MODE == 0 && deg == 0) { ax = 0.f; ay = 0.f; }
    if (MODE == 2) {
        float inv = 1.f / (float)(deg > 1 ? deg : 1);
        ax *= inv; ay *= inv;
    }
    float2 self = h2f2(*(const unsigned int*)(h + (size_t)node * FEAT + 2 * lane));
    float sc = 1.f + eps[ei];
    float ox = fmaf(sc, self.x, ax);
    float oy = fmaf(sc, self.y, ay);
    *(unsigned int*)(out + (size_t)node * FEAT + 2 * lane) = f2h2(ox, oy);
}

// ---------------------------------------------------------------- MFMA GEMM
// Y = relu?(X[M][128] @ W[128][BN] + bias); X f16, WT f16 [BN][128]
// BM=128 rows/block, 4 waves, each wave 32 rows x BN cols.
template <int BN, bool RELU, bool OUTF32>
__global__ __launch_bounds__(256, 2) void gemm_mfma(const _Float16* __restrict__ X,
                                                    const _Float16* __restrict__ WT,
                                                    const float* __restrict__ bias,
                                                    _Float16* __restrict__ Yh,
                                                    float* __restrict__ Yf) {
    __shared__ _Float16 Xs[128 * 128];
    __shared__ _Float16 Ws[BN * 128];
    char* xb = (char*)Xs;
    char* wb = (char*)Ws;

    int t = threadIdx.x;
    int l = t & 63, w = t >> 6;
    int lr = l & 15, lg = l >> 4;
    int rowBase = blockIdx.x * 128;

    // stage X tile (swizzled: byte ^= (row&7)<<4 within each 256B row)
    // 2 threads per row, each stages 128 bytes (8 x half8)
    {
        int row = t >> 1, hf = t & 1;
        int grow = rowBase + row;
        const char* src = (const char*)(X + (size_t)grow * 128 + hf * 64);
#pragma unroll
        for (int j = 0; j < 8; ++j) {
            int byte = hf * 128 + j * 16;
            half8 v = {};
            if (grow < N_NODES) v = *(const half8*)(src + j * 16);
            *(half8*)(xb + row * 256 + (byte ^ ((row & 7) << 4))) = v;
        }
    }
    // stage WT tile (same swizzle); BN*2 threads participate
    if (t < BN * 2) {
        int row = t >> 1, hf = t & 1;
        const char* src = (const char*)(WT + (size_t)row * 128 + hf * 64);
#pragma unroll
        for (int j = 0; j < 8; ++j) {
            int byte = hf * 128 + j * 16;
            *(half8*)(wb + row * 256 + (byte ^ ((row & 7) << 4))) =
                *(const half8*)(src + j * 16);
        }
    }
    __syncthreads();

    constexpr int NCT = BN / 16;
    floatx4 acc[2][NCT];
#pragma unroll
    for (int rt = 0; rt < 2; ++rt)
#pragma unroll
        for (int ct = 0; ct < NCT; ++ct)
#pragma unroll
            for (int r = 0; r < 4; ++r) acc[rt][ct][r] = 0.f;

#pragma unroll
    for (int ks = 0; ks < 4; ++ks) {
        int kbyte = ks * 64 + lg * 16;
        half8 a[2];
#pragma unroll
        for (int rt = 0; rt < 2; ++rt) {
            int r = w * 32 + rt * 16 + lr;
            a[rt] = *(const half8*)(xb + r * 256 + (kbyte ^ ((r & 7) << 4)));
        }
#pragma unroll
        for (int ct = 0; ct < NCT; ++ct) {
            int n = ct * 16 + lr;
            half8 b = *(const half8*)(wb + n * 256 + (kbyte ^ ((n & 7) << 4)));
            acc[0][ct] = __builtin_amdgcn_mfma_f32_16x16x32_f16(a[0], b, acc[0][ct], 0, 0, 0);
            acc[1][ct] = __builtin_amdgcn_mfma_f32_16x16x32_f16(a[1], b, acc[1][ct], 0, 0, 0);
        }
    }

    float bv[NCT];
#pragma unroll
    for (int ct = 0; ct < NCT; ++ct) bv[ct] = bias[ct * 16 + lr];

    if (OUTF32) {
        // direct f32 stores (final layer)
#pragma unroll
        for (int rt = 0; rt < 2; ++rt)
#pragma unroll
            for (int ct = 0; ct < NCT; ++ct)
#pragma unroll
                for (int r = 0; r < 4; ++r) {
                    int row = rowBase + w * 32 + rt * 16 + lg * 4 + r;
                    if (row < N_NODES) {
                        float v = acc[rt][ct][r] + bv[ct];
                        if (RELU) v = fmaxf(v, 0.f);
                        Yf[(size_t)row * BN + ct * 16 + lr] = v;
                    }
                }
    } else {
        // bounce through LDS (reuse Xs) for coalesced f16 stores
        __syncthreads();
#pragma unroll
        for (int rt = 0; rt < 2; ++rt)
#pragma unroll
            for (int ct = 0; ct < NCT; ++ct)
#pragma unroll
                for (int r = 0; r < 4; ++r) {
                    int row = w * 32 + rt * 16 + lg * 4 + r;
                    int col = ct * 16 + lr;
                    float v = acc[rt][ct][r] + bv[ct];
                    if (RELU) v = fmaxf(v, 0.f);
                    *(_Float16*)(xb + row * 256 + ((col * 2) ^ ((row & 7) << 4))) =
                        (_Float16)v;
                }
        __syncthreads();
        int row = t >> 1, hf = t & 1;
        int grow = rowBase + row;
        if (grow < N_NODES) {
            char* dstp = (char*)(Yh + (size_t)grow * 128 + hf * 64);
#pragma unroll
            for (int j = 0; j < 8; ++j) {
                int byte = hf * 128 + j * 16;
                half8 v = *(const half8*)(xb + row * 256 + (byte ^ ((row & 7) << 4)));
                *(half8*)(dstp + j * 16) = v;
            }
        }
    }
}

// ---------------------------------------------------------------- launch
extern "C" void kernel_launch(void* const* d_in, const int* in_sizes, int n_in,
                              void* d_out, int out_size, void* d_ws, size_t ws_size,
                              hipStream_t stream) {
    const float* feat = (const float*)d_in[0];
    const int*   src  = (const int*)d_in[1];
    const int*   dst  = (const int*)d_in[2];
    const float* W1   = (const float*)d_in[3];
    const float* b1   = (const float*)d_in[4];
    const float* W2a  = (const float*)d_in[5];
    const float* b2a  = (const float*)d_in[6];
    const float* W2b  = (const float*)d_in[7];
    const float* b2b  = (const float*)d_in[8];
    const float* W3   = (const float*)d_in[9];
    const float* b3   = (const float*)d_in[10];
    const float* eps  = (const float*)d_in[11];

    const size_t NH = (size_t)N_NODES * FEAT;  // 12.8M halves
    _Float16* featH = (_Float16*)d_ws;
    _Float16* hA    = featH + NH;
    _Float16* hB    = hA + NH;
    _Float16* WT1   = hB + NH;
    _Float16* WT2a  = WT1 + 128 * 128;
    _Float16* WT2b  = WT2a + 128 * 128;
    _Float16* WT3   = WT2b + 128 * 128;
    int* rowptr = (int*)(WT3 + 128 * 64);
    int* cursor = rowptr + (N_NODES + 1);
    int* esrc   = cursor + N_NODES;
    int* bsums  = esrc + N_EDGES;

    const int NCHUNK = (N_NODES + 1023) / 1024;  // 98

    // --- preps: feature & weight conversion
    f32_to_f16_vec<<<2048, 256, 0, stream>>>(feat, featH, (int)(NH / 4));
    wprep<<<64, 256, 0, stream>>>(W1, WT1, 128, 128);
    wprep<<<64, 256, 0, stream>>>(W2a, WT2a, 128, 128);
    wprep<<<64, 256, 0, stream>>>(W2b, WT2b, 128, 128);
    wprep<<<32, 256, 0, stream>>>(W3, WT3, 128, 64);

    // --- build CSR (dst-sorted incoming edges)
    zero_i32<<<(N_NODES + 255) / 256, 256, 0, stream>>>(cursor, N_NODES);
    count_deg<<<(N_EDGES + 255) / 256, 256, 0, stream>>>(dst, cursor);
    scan_chunks<<<NCHUNK, 1024, 0, stream>>>(cursor, rowptr + 1, bsums);
    scan_totals<<<1, 128, 0, stream>>>(bsums, NCHUNK);
    finish_scan<<<NCHUNK, 1024, 0, stream>>>(rowptr, bsums, cursor);
    fill_csr<<<(N_EDGES + 255) / 256, 256, 0, stream>>>(src, dst, rowptr, cursor, esrc);

    const int AGG_GRID = (N_NODES * 64 + 255) / 256;  // 1 wave per node
    const int GEMM_GRID = (N_NODES + 127) / 128;      // 782

    // layer 0: max agg + W1 + relu
    agg_kernel<0><<<AGG_GRID, 256, 0, stream>>>(featH, rowptr, esrc, eps, 0, hB);
    gemm_mfma<128, true, false><<<GEMM_GRID, 256, 0, stream>>>(hB, WT1, b1, hA, nullptr);
    // layer 1: sum agg + W2a + relu
    agg_kernel<1><<<AGG_GRID, 256, 0, stream>>>(hA, rowptr, esrc, eps, 1, hB);
    gemm_mfma<128, true, false><<<GEMM_GRID, 256, 0, stream>>>(hB, WT2a, b2a, hA, nullptr);
    // layer 2: sum agg + W2b + relu
    agg_kernel<1><<<AGG_GRID, 256, 0, stream>>>(hA, rowptr, esrc, eps, 2, hB);
    gemm_mfma<128, true, false><<<GEMM_GRID, 256, 0, stream>>>(hB, WT2b, b2b, hA, nullptr);
    // layer 3: mean agg + W3 (no relu, f32 out)
    agg_kernel<2><<<AGG_GRID, 256, 0, stream>>>(hA, rowptr, esrc, eps, 3, hB);
    gemm_mfma<64, false, true><<<GEMM_GRID, 256, 0, stream>>>(hB, WT3, b3, nullptr, (float*)d_out);
}

// Round 4
// 416.260 us; speedup vs baseline: 2.0600x; 1.3582x over previous
//
#include <hip/hip_runtime.h>
#include <math.h>

#define N_NODES 100000
#define N_EDGES 1600000
#define FEAT 128
#define NBUCKET 391   // ceil(N_NODES/256)
#define BCAP 5120     // max edges per 256-node bucket (mean 4096, std ~64)

typedef __attribute__((ext_vector_type(8))) _Float16 half8;
typedef __attribute__((ext_vector_type(4))) float floatx4;

__device__ inline float2 h2f2(unsigned int u) {
    union { unsigned int u; _Float16 h[2]; } x; x.u = u;
    return make_float2((float)x.h[0], (float)x.h[1]);
}
__device__ inline unsigned int f2h2(float a, float b) {
    union { unsigned int u; _Float16 h[2]; } x;
    x.h[0] = (_Float16)a; x.h[1] = (_Float16)b; return x.u;
}

// ---------------------------------------------------------------- utilities
__global__ __launch_bounds__(256) void zero_i32(int* p, int n) {
    int i = blockIdx.x * 256 + threadIdx.x;
    if (i < n) p[i] = 0;
}

// ---------------------------------------------------------------- bucketed CSR
// Phase 1: bin edges into per-bucket arenas with block-local chunk reservation.
__global__ __launch_bounds__(512) void bin_edges(const int* __restrict__ src,
                                                 const int* __restrict__ dst,
                                                 uint2* __restrict__ ebuf,
                                                 int* __restrict__ gcur) {
    __shared__ int hist[NBUCKET];
    __shared__ int lbase[NBUCKET];
    __shared__ int cur[NBUCKET];
    __shared__ uint2 tile[4096];

    int t = threadIdx.x;
    int e0 = blockIdx.x * 4096;
    for (int i = t; i < NBUCKET; i += 512) { hist[i] = 0; cur[i] = 0; }
    __syncthreads();

    for (int i = t; i < 4096; i += 512) {
        int e = e0 + i;
        uint2 v; v.x = 0u; v.y = 0xffffffffu;
        if (e < N_EDGES) { v.x = (unsigned)src[e]; v.y = (unsigned)dst[e]; }
        tile[i] = v;
        if (v.y != 0xffffffffu) atomicAdd(&hist[v.y >> 8], 1);
    }
    __syncthreads();

    for (int i = t; i < NBUCKET; i += 512) {
        int c = hist[i];
        lbase[i] = (c > 0) ? atomicAdd(&gcur[i], c) : 0;
    }
    __syncthreads();

    for (int i = t; i < 4096; i += 512) {
        uint2 v = tile[i];
        if (v.y == 0xffffffffu) continue;
        int b = (int)(v.y >> 8);
        int p = lbase[b] + atomicAdd(&cur[b], 1);
        if (p < BCAP) ebuf[(size_t)b * BCAP + p] = v;
    }
}

// Phase 2: exclusive scan of bucket totals -> bbase; also rowptr[N] = E.
__global__ __launch_bounds__(512) void scan_buckets(const int* __restrict__ gcur,
                                                    int* __restrict__ bbase,
                                                    int* __restrict__ rowptr) {
    __shared__ int s[512];
    int t = threadIdx.x;
    int v = (t < NBUCKET) ? gcur[t] : 0;
    s[t] = v;
    __syncthreads();
    for (int off = 1; off < 512; off <<= 1) {
        int u = (t >= off) ? s[t - off] : 0;
        __syncthreads();
        s[t] += u;
        __syncthreads();
    }
    if (t < NBUCKET) bbase[t] = s[t] - v;
    if (t == 0) rowptr[N_NODES] = N_EDGES;
}

// Phase 3: per-bucket local CSR: rowptr for its 256 nodes + esrc scatter
// (scatter stays within the bucket's ~16-40KB esrc window -> L2-local).
__global__ __launch_bounds__(256) void bucket_csr(const uint2* __restrict__ ebuf,
                                                  const int* __restrict__ gcur,
                                                  const int* __restrict__ bbase,
                                                  int* __restrict__ rowptr,
                                                  int* __restrict__ esrc) {
    __shared__ int cnt[256];
    __shared__ int off[256];
    __shared__ int astart[256];
    __shared__ int cur[256];

    int b = blockIdx.x, t = threadIdx.x;
    int total = gcur[b]; if (total > BCAP) total = BCAP;
    int base = bbase[b];
    const uint2* eb = ebuf + (size_t)b * BCAP;

    cnt[t] = 0; cur[t] = 0;
    __syncthreads();
    for (int i = t; i < total; i += 256) atomicAdd(&cnt[eb[i].y & 255], 1);
    __syncthreads();

    int v = cnt[t];
    off[t] = v;
    __syncthreads();
    for (int o = 1; o < 256; o <<= 1) {
        int u = (t >= o) ? off[t - o] : 0;
        __syncthreads();
        off[t] += u;
        __syncthreads();
    }
    int excl = off[t] - v;          // exclusive prefix within bucket
    int node = (b << 8) + t;
    if (node < N_NODES) rowptr[node] = base + excl;
    astart[t] = base + excl;
    __syncthreads();

    for (int i = t; i < total; i += 256) {
        uint2 e = eb[i];
        int ln = (int)(e.y & 255);
        int p = astart[ln] + atomicAdd(&cur[ln], 1);
        esrc[p] = (int)e.x;
    }
}

// ---------------------------------------------------------------- conversions
__global__ __launch_bounds__(256) void f32_to_f16_vec(const float* __restrict__ in,
                                                      _Float16* __restrict__ out,
                                                      int n4) {
    int i = blockIdx.x * 256 + threadIdx.x;
    int stride = gridDim.x * 256;
    for (; i < n4; i += stride) {
        float4 v = ((const float4*)in)[i];
        union { uint2 u; _Float16 h[4]; } p;
        p.h[0] = (_Float16)v.x; p.h[1] = (_Float16)v.y;
        p.h[2] = (_Float16)v.z; p.h[3] = (_Float16)v.w;
        *(uint2*)(out + 4 * (size_t)i) = p.u;
    }
}

// W f32 [K][N] -> WT f16 [N][K]
__global__ __launch_bounds__(256) void wprep(const float* __restrict__ W,
                                             _Float16* __restrict__ WT,
                                             int K, int N) {
    int idx = blockIdx.x * 256 + threadIdx.x;
    if (idx < K * N) {
        int n = idx / K, k = idx % K;
        WT[idx] = (_Float16)W[k * N + n];
    }
}

// ---------------------------------------------------------------- aggregation
// MODE: 0=max (0 if deg==0), 1=sum, 2=mean ; h, out are f16 [N][128]
template <int MODE>
__global__ __launch_bounds__(256) void agg_kernel(const _Float16* __restrict__ h,
                                                  const int* __restrict__ rowptr,
                                                  const int* __restrict__ esrc,
                                                  const float* __restrict__ eps,
                                                  int ei,
                                                  _Float16* __restrict__ out) {
    int node = (int)((blockIdx.x * 256 + threadIdx.x) >> 6);
    int lane = threadIdx.x & 63;
    if (node >= N_NODES) return;
    int beg = rowptr[node], end = rowptr[node + 1];

    float ax = (MODE == 0) ? -INFINITY : 0.f;
    float ay = ax;

    int e = beg;
    // 8 rows in flight for latency hiding
    for (; e + 8 <= end; e += 8) {
        unsigned int u[8];
#pragma unroll
        for (int j = 0; j < 8; ++j) {
            int s = esrc[e + j];
            u[j] = *(const unsigned int*)(h + (size_t)s * FEAT + 2 * lane);
        }
#pragma unroll
        for (int j = 0; j < 8; ++j) {
            float2 v = h2f2(u[j]);
            if (MODE == 0) { ax = fmaxf(ax, v.x); ay = fmaxf(ay, v.y); }
            else           { ax += v.x; ay += v.y; }
        }
    }
    for (; e + 2 <= end; e += 2) {
        int s0 = esrc[e], s1 = esrc[e + 1];
        unsigned int u0 = *(const unsigned int*)(h + (size_t)s0 * FEAT + 2 * lane);
        unsigned int u1 = *(const unsigned int*)(h + (size_t)s1 * FEAT + 2 * lane);
        float2 v0 = h2f2(u0), v1 = h2f2(u1);
        if (MODE == 0) { ax = fmaxf(ax, fmaxf(v0.x, v1.x)); ay = fmaxf(ay, fmaxf(v0.y, v1.y)); }
        else           { ax += v0.x + v1.x; ay += v0.y + v1.y; }
    }
    for (; e < end; ++e) {
        int s0 = esrc[e];
        float2 v0 = h2f2(*(const unsigned int*)(h + (size_t)s0 * FEAT + 2 * lane));
        if (MODE == 0) { ax = fmaxf(ax, v0.x); ay = fmaxf(ay, v0.y); }
        else           { ax += v0.x; ay += v0.y; }
    }

    int deg = end - beg;
    if (MODE == 0 && deg == 0) { ax = 0.f; ay = 0.f; }
    if (MODE == 2) {
        float inv = 1.f / (float)(deg > 1 ? deg : 1);
        ax *= inv; ay *= inv;
    }
    float2 self = h2f2(*(const unsigned int*)(h + (size_t)node * FEAT + 2 * lane));
    float sc = 1.f + eps[ei];
    float ox = fmaf(sc, self.x, ax);
    float oy = fmaf(sc, self.y, ay);
    *(unsigned int*)(out + (size_t)node * FEAT + 2 * lane) = f2h2(ox, oy);
}

// ---------------------------------------------------------------- MFMA GEMM
// Y = relu?(X[M][128] @ W[128][BN] + bias); X f16, WT f16 [BN][128]
template <int BN, bool RELU, bool OUTF32>
__global__ __launch_bounds__(256, 2) void gemm_mfma(const _Float16* __restrict__ X,
                                                    const _Float16* __restrict__ WT,
                                                    const float* __restrict__ bias,
                                                    _Float16* __restrict__ Yh,
                                                    float* __restrict__ Yf) {
    __shared__ _Float16 Xs[128 * 128];
    __shared__ _Float16 Ws[BN * 128];
    char* xb = (char*)Xs;
    char* wb = (char*)Ws;

    int t = threadIdx.x;
    int l = t & 63, w = t >> 6;
    int lr = l & 15, lg = l >> 4;
    int rowBase = blockIdx.x * 128;

    // stage X tile (swizzled: byte ^= (row&7)<<4 within each 256B row)
    {
        int row = t >> 1, hf = t & 1;
        int grow = rowBase + row;
        const char* src = (const char*)(X + (size_t)grow * 128 + hf * 64);
#pragma unroll
        for (int j = 0; j < 8; ++j) {
            int byte = hf * 128 + j * 16;
            half8 v = {};
            if (grow < N_NODES) v = *(const half8*)(src + j * 16);
            *(half8*)(xb + row * 256 + (byte ^ ((row & 7) << 4))) = v;
        }
    }
    if (t < BN * 2) {
        int row = t >> 1, hf = t & 1;
        const char* src = (const char*)(WT + (size_t)row * 128 + hf * 64);
#pragma unroll
        for (int j = 0; j < 8; ++j) {
            int byte = hf * 128 + j * 16;
            *(half8*)(wb + row * 256 + (byte ^ ((row & 7) << 4))) =
                *(const half8*)(src + j * 16);
        }
    }
    __syncthreads();

    constexpr int NCT = BN / 16;
    floatx4 acc[2][NCT];
#pragma unroll
    for (int rt = 0; rt < 2; ++rt)
#pragma unroll
        for (int ct = 0; ct < NCT; ++ct)
#pragma unroll
            for (int r = 0; r < 4; ++r) acc[rt][ct][r] = 0.f;

#pragma unroll
    for (int ks = 0; ks < 4; ++ks) {
        int kbyte = ks * 64 + lg * 16;
        half8 a[2];
#pragma unroll
        for (int rt = 0; rt < 2; ++rt) {
            int r = w * 32 + rt * 16 + lr;
            a[rt] = *(const half8*)(xb + r * 256 + (kbyte ^ ((r & 7) << 4)));
        }
#pragma unroll
        for (int ct = 0; ct < NCT; ++ct) {
            int n = ct * 16 + lr;
            half8 b = *(const half8*)(wb + n * 256 + (kbyte ^ ((n & 7) << 4)));
            acc[0][ct] = __builtin_amdgcn_mfma_f32_16x16x32_f16(a[0], b, acc[0][ct], 0, 0, 0);
            acc[1][ct] = __builtin_amdgcn_mfma_f32_16x16x32_f16(a[1], b, acc[1][ct], 0, 0, 0);
        }
    }

    float bv[NCT];
#pragma unroll
    for (int ct = 0; ct < NCT; ++ct) bv[ct] = bias[ct * 16 + lr];

    if (OUTF32) {
#pragma unroll
        for (int rt = 0; rt < 2; ++rt)
#pragma unroll
            for (int ct = 0; ct < NCT; ++ct)
#pragma unroll
                for (int r = 0; r < 4; ++r) {
                    int row = rowBase + w * 32 + rt * 16 + lg * 4 + r;
                    if (row < N_NODES) {
                        float v = acc[rt][ct][r] + bv[ct];
                        if (RELU) v = fmaxf(v, 0.f);
                        Yf[(size_t)row * BN + ct * 16 + lr] = v;
                    }
                }
    } else {
        __syncthreads();
#pragma unroll
        for (int rt = 0; rt < 2; ++rt)
#pragma unroll
            for (int ct = 0; ct < NCT; ++ct)
#pragma unroll
                for (int r = 0; r < 4; ++r) {
                    int row = w * 32 + rt * 16 + lg * 4 + r;
                    int col = ct * 16 + lr;
                    float v = acc[rt][ct][r] + bv[ct];
                    if (RELU) v = fmaxf(v, 0.f);
                    *(_Float16*)(xb + row * 256 + ((col * 2) ^ ((row & 7) << 4))) =
                        (_Float16)v;
                }
        __syncthreads();
        int row = t >> 1, hf = t & 1;
        int grow = rowBase + row;
        if (grow < N_NODES) {
            char* dstp = (char*)(Yh + (size_t)grow * 128 + hf * 64);
#pragma unroll
            for (int j = 0; j < 8; ++j) {
                int byte = hf * 128 + j * 16;
                half8 v = *(const half8*)(xb + row * 256 + (byte ^ ((row & 7) << 4)));
                *(half8*)(dstp + j * 16) = v;
            }
        }
    }
}

// ---------------------------------------------------------------- launch
extern "C" void kernel_launch(void* const* d_in, const int* in_sizes, int n_in,
                              void* d_out, int out_size, void* d_ws, size_t ws_size,
                              hipStream_t stream) {
    const float* feat = (const float*)d_in[0];
    const int*   src  = (const int*)d_in[1];
    const int*   dst  = (const int*)d_in[2];
    const float* W1   = (const float*)d_in[3];
    const float* b1   = (const float*)d_in[4];
    const float* W2a  = (const float*)d_in[5];
    const float* b2a  = (const float*)d_in[6];
    const float* W2b  = (const float*)d_in[7];
    const float* b2b  = (const float*)d_in[8];
    const float* W3   = (const float*)d_in[9];
    const float* b3   = (const float*)d_in[10];
    const float* eps  = (const float*)d_in[11];

    const size_t NH = (size_t)N_NODES * FEAT;
    char* base = (char*)d_ws;
    auto alloc = [&](size_t bytes) {
        char* p = base;
        base += (bytes + 255) & ~(size_t)255;
        return p;
    };
    _Float16* featH = (_Float16*)alloc(NH * 2);
    _Float16* hA    = (_Float16*)alloc(NH * 2);
    _Float16* hB    = (_Float16*)alloc(NH * 2);
    _Float16* WT1   = (_Float16*)alloc(128 * 128 * 2);
    _Float16* WT2a  = (_Float16*)alloc(128 * 128 * 2);
    _Float16* WT2b  = (_Float16*)alloc(128 * 128 * 2);
    _Float16* WT3   = (_Float16*)alloc(128 * 64 * 2);
    uint2* ebuf     = (uint2*)alloc((size_t)NBUCKET * BCAP * 8);
    int* rowptr     = (int*)alloc((N_NODES + 1) * 4);
    int* esrc       = (int*)alloc((size_t)N_EDGES * 4);
    int* gcur       = (int*)alloc(NBUCKET * 4);
    int* bbase      = (int*)alloc(NBUCKET * 4);

    // --- preps: feature & weight conversion
    f32_to_f16_vec<<<2048, 256, 0, stream>>>(feat, featH, (int)(NH / 4));
    wprep<<<64, 256, 0, stream>>>(W1, WT1, 128, 128);
    wprep<<<64, 256, 0, stream>>>(W2a, WT2a, 128, 128);
    wprep<<<64, 256, 0, stream>>>(W2b, WT2b, 128, 128);
    wprep<<<32, 256, 0, stream>>>(W3, WT3, 128, 64);

    // --- bucketed CSR build
    zero_i32<<<(NBUCKET + 255) / 256, 256, 0, stream>>>(gcur, NBUCKET);
    bin_edges<<<(N_EDGES + 4095) / 4096, 512, 0, stream>>>(src, dst, ebuf, gcur);
    scan_buckets<<<1, 512, 0, stream>>>(gcur, bbase, rowptr);
    bucket_csr<<<NBUCKET, 256, 0, stream>>>(ebuf, gcur, bbase, rowptr, esrc);

    const int AGG_GRID = (N_NODES * 64 + 255) / 256;  // 1 wave per node
    const int GEMM_GRID = (N_NODES + 127) / 128;      // 782

    // layer 0: max agg + W1 + relu
    agg_kernel<0><<<AGG_GRID, 256, 0, stream>>>(featH, rowptr, esrc, eps, 0, hB);
    gemm_mfma<128, true, false><<<GEMM_GRID, 256, 0, stream>>>(hB, WT1, b1, hA, nullptr);
    // layer 1: sum agg + W2a + relu
    agg_kernel<1><<<AGG_GRID, 256, 0, stream>>>(hA, rowptr, esrc, eps, 1, hB);
    gemm_mfma<128, true, false><<<GEMM_GRID, 256, 0, stream>>>(hB, WT2a, b2a, hA, nullptr);
    // layer 2: sum agg + W2b + relu
    agg_kernel<1><<<AGG_GRID, 256, 0, stream>>>(hA, rowptr, esrc, eps, 2, hB);
    gemm_mfma<128, true, false><<<GEMM_GRID, 256, 0, stream>>>(hB, WT2b, b2b, hA, nullptr);
    // layer 3: mean agg + W3 (no relu, f32 out)
    agg_kernel<2><<<AGG_GRID, 256, 0, stream>>>(hA, rowptr, esrc, eps, 3, hB);
    gemm_mfma<64, false, true><<<GEMM_GRID, 256, 0, stream>>>(hB, WT3, b3, nullptr, (float*)d_out);
}

// Round 5
// 387.605 us; speedup vs baseline: 2.2123x; 1.0739x over previous
//
#include <hip/hip_runtime.h>
#include <math.h>

#define N_NODES 100000
#define N_EDGES 1600000
#define FEAT 128
#define NBUCKET 391   // ceil(N_NODES/256)
#define BCAP 5120     // max edges per 256-node bucket (mean 4096)

typedef __attribute__((ext_vector_type(8))) _Float16 half8;
typedef __attribute__((ext_vector_type(4))) float floatx4;

// ---------------------------------------------------------------- utilities
__global__ __launch_bounds__(256) void zero_i32(int* p, int n) {
    int i = blockIdx.x * 256 + threadIdx.x;
    if (i < n) p[i] = 0;
}

// ---------------------------------------------------------------- bucketed CSR
__global__ __launch_bounds__(512) void bin_edges(const int* __restrict__ src,
                                                 const int* __restrict__ dst,
                                                 uint2* __restrict__ ebuf,
                                                 int* __restrict__ gcur) {
    __shared__ int hist[NBUCKET];
    __shared__ int lbase[NBUCKET];
    __shared__ int cur[NBUCKET];
    __shared__ uint2 tile[4096];

    int t = threadIdx.x;
    int e0 = blockIdx.x * 4096;
    for (int i = t; i < NBUCKET; i += 512) { hist[i] = 0; cur[i] = 0; }
    __syncthreads();

    for (int i = t; i < 4096; i += 512) {
        int e = e0 + i;
        uint2 v; v.x = 0u; v.y = 0xffffffffu;
        if (e < N_EDGES) { v.x = (unsigned)src[e]; v.y = (unsigned)dst[e]; }
        tile[i] = v;
        if (v.y != 0xffffffffu) atomicAdd(&hist[v.y >> 8], 1);
    }
    __syncthreads();

    for (int i = t; i < NBUCKET; i += 512) {
        int c = hist[i];
        lbase[i] = (c > 0) ? atomicAdd(&gcur[i], c) : 0;
    }
    __syncthreads();

    for (int i = t; i < 4096; i += 512) {
        uint2 v = tile[i];
        if (v.y == 0xffffffffu) continue;
        int b = (int)(v.y >> 8);
        int p = lbase[b] + atomicAdd(&cur[b], 1);
        if (p < BCAP) ebuf[(size_t)b * BCAP + p] = v;
    }
}

__global__ __launch_bounds__(512) void scan_buckets(const int* __restrict__ gcur,
                                                    int* __restrict__ bbase,
                                                    int* __restrict__ rowptr) {
    __shared__ int s[512];
    int t = threadIdx.x;
    int v = (t < NBUCKET) ? gcur[t] : 0;
    s[t] = v;
    __syncthreads();
    for (int off = 1; off < 512; off <<= 1) {
        int u = (t >= off) ? s[t - off] : 0;
        __syncthreads();
        s[t] += u;
        __syncthreads();
    }
    if (t < NBUCKET) bbase[t] = s[t] - v;
    if (t == 0) rowptr[N_NODES] = N_EDGES;
}

__global__ __launch_bounds__(256) void bucket_csr(const uint2* __restrict__ ebuf,
                                                  const int* __restrict__ gcur,
                                                  const int* __restrict__ bbase,
                                                  int* __restrict__ rowptr,
                                                  int* __restrict__ esrc) {
    __shared__ int cnt[256];
    __shared__ int off[256];
    __shared__ int astart[256];
    __shared__ int cur[256];

    int b = blockIdx.x, t = threadIdx.x;
    int total = gcur[b]; if (total > BCAP) total = BCAP;
    int base = bbase[b];
    const uint2* eb = ebuf + (size_t)b * BCAP;

    cnt[t] = 0; cur[t] = 0;
    __syncthreads();
    for (int i = t; i < total; i += 256) atomicAdd(&cnt[eb[i].y & 255], 1);
    __syncthreads();

    int v = cnt[t];
    off[t] = v;
    __syncthreads();
    for (int o = 1; o < 256; o <<= 1) {
        int u = (t >= o) ? off[t - o] : 0;
        __syncthreads();
        off[t] += u;
        __syncthreads();
    }
    int excl = off[t] - v;
    int node = (b << 8) + t;
    if (node < N_NODES) rowptr[node] = base + excl;
    astart[t] = base + excl;
    __syncthreads();

    for (int i = t; i < total; i += 256) {
        uint2 e = eb[i];
        int ln = (int)(e.y & 255);
        int p = astart[ln] + atomicAdd(&cur[ln], 1);
        esrc[p] = (int)e.x;
    }
}

// ---------------------------------------------------------------- conversions
__global__ __launch_bounds__(256) void f32_to_f16_vec(const float* __restrict__ in,
                                                      _Float16* __restrict__ out,
                                                      int n4) {
    int i = blockIdx.x * 256 + threadIdx.x;
    int stride = gridDim.x * 256;
    for (; i < n4; i += stride) {
        float4 v = ((const float4*)in)[i];
        union { uint2 u; _Float16 h[4]; } p;
        p.h[0] = (_Float16)v.x; p.h[1] = (_Float16)v.y;
        p.h[2] = (_Float16)v.z; p.h[3] = (_Float16)v.w;
        *(uint2*)(out + 4 * (size_t)i) = p.u;
    }
}

// W f32 [K][N] -> WT f16 [N][K]
__global__ __launch_bounds__(256) void wprep(const float* __restrict__ W,
                                             _Float16* __restrict__ WT,
                                             int K, int N) {
    int idx = blockIdx.x * 256 + threadIdx.x;
    if (idx < K * N) {
        int n = idx / K, k = idx % K;
        WT[idx] = (_Float16)W[k * N + n];
    }
}

// ---------------------------------------------------------------- aggregation
// One wave per node. Edge rows (D f16 = D*2 bytes) are read by LPE-lane
// groups, 16B per lane -> NG edges per wave-load. Cross-group combine via
// shfl_xor. MODE: 0=max(0 if deg==0), 1=sum, 2=mean.
// out = (1+eps)*h[n] + agg ; +bias and f32 out when OUTF32.
template <int MODE, int D, bool OUTF32, bool BIAS>
__global__ __launch_bounds__(256) void agg_kernel(const _Float16* __restrict__ h,
                                                  const int* __restrict__ rowptr,
                                                  const int* __restrict__ esrc,
                                                  const float* __restrict__ eps,
                                                  int ei,
                                                  const float* __restrict__ bias,
                                                  _Float16* __restrict__ outH,
                                                  float* __restrict__ outF) {
    constexpr int LPE = D / 8;    // lanes per edge-row (16B each)
    constexpr int NG = 64 / LPE;  // edges per wave-iteration
    int node = (int)((blockIdx.x * 256 + threadIdx.x) >> 6);
    if (node >= N_NODES) return;
    int l = threadIdx.x & 63;
    int grp = l / LPE, sl = l & (LPE - 1);
    int beg = rowptr[node], end = rowptr[node + 1];
    int deg = end - beg;

    float a[8];
#pragma unroll
    for (int i = 0; i < 8; ++i) a[i] = (MODE == 0) ? -INFINITY : 0.f;

    int e = beg;
    for (; e + 2 * NG <= end; e += 2 * NG) {
        int s0 = esrc[e + grp];
        int s1 = esrc[e + NG + grp];
        half8 v0 = *(const half8*)(h + (size_t)s0 * D + sl * 8);
        half8 v1 = *(const half8*)(h + (size_t)s1 * D + sl * 8);
#pragma unroll
        for (int i = 0; i < 8; ++i) {
            float f0 = (float)v0[i], f1 = (float)v1[i];
            if (MODE == 0) a[i] = fmaxf(a[i], fmaxf(f0, f1));
            else           a[i] += f0 + f1;
        }
    }
    for (; e < end; e += NG) {
        int ee = e + grp;
        if (ee < end) {
            int s = esrc[ee];
            half8 v = *(const half8*)(h + (size_t)s * D + sl * 8);
#pragma unroll
            for (int i = 0; i < 8; ++i) {
                float f = (float)v[i];
                if (MODE == 0) a[i] = fmaxf(a[i], f);
                else           a[i] += f;
            }
        }
    }

    // combine edge groups: lanes {l, l^LPE, l^2LPE, ...}
#pragma unroll
    for (int m = LPE; m < 64; m <<= 1) {
#pragma unroll
        for (int i = 0; i < 8; ++i) {
            float o = __shfl_xor(a[i], m, 64);
            a[i] = (MODE == 0) ? fmaxf(a[i], o) : (a[i] + o);
        }
    }

    if (grp != 0) return;
    if (MODE == 0 && deg == 0) {
#pragma unroll
        for (int i = 0; i < 8; ++i) a[i] = 0.f;
    }
    if (MODE == 2) {
        float inv = 1.f / (float)(deg > 0 ? deg : 1);
#pragma unroll
        for (int i = 0; i < 8; ++i) a[i] *= inv;
    }
    float sc = 1.f + eps[ei];
    half8 self = *(const half8*)(h + (size_t)node * D + sl * 8);
    float o[8];
#pragma unroll
    for (int i = 0; i < 8; ++i) o[i] = fmaf(sc, (float)self[i], a[i]);

    if (OUTF32) {
#pragma unroll
        for (int i = 0; i < 8; ++i)
            if (BIAS) o[i] += bias[sl * 8 + i];
        float4* dstp = (float4*)(outF + (size_t)node * D + sl * 8);
        dstp[0] = make_float4(o[0], o[1], o[2], o[3]);
        dstp[1] = make_float4(o[4], o[5], o[6], o[7]);
    } else {
        half8 ov;
#pragma unroll
        for (int i = 0; i < 8; ++i) ov[i] = (_Float16)o[i];
        *(half8*)(outH + (size_t)node * D + sl * 8) = ov;
    }
}

// ---------------------------------------------------------------- MFMA GEMM
// Y = act(X[M][128] @ W[128][BN] (+bias)); X f16, WT f16 [BN][128]
template <int BN, bool RELU, bool BIAS>
__global__ __launch_bounds__(256, 2) void gemm_mfma(const _Float16* __restrict__ X,
                                                    const _Float16* __restrict__ WT,
                                                    const float* __restrict__ bias,
                                                    _Float16* __restrict__ Yh) {
    __shared__ _Float16 Xs[128 * 128];
    __shared__ _Float16 Ws[BN * 128];
    char* xb = (char*)Xs;
    char* wb = (char*)Ws;

    int t = threadIdx.x;
    int l = t & 63, w = t >> 6;
    int lr = l & 15, lg = l >> 4;
    int rowBase = blockIdx.x * 128;

    // stage X tile (swizzle byte ^= (row&7)<<4 within each 256B row)
    {
        int row = t >> 1, hf = t & 1;
        int grow = rowBase + row;
        const char* srcp = (const char*)(X + (size_t)grow * 128 + hf * 64);
#pragma unroll
        for (int j = 0; j < 8; ++j) {
            int byte = hf * 128 + j * 16;
            half8 v = {};
            if (grow < N_NODES) v = *(const half8*)(srcp + j * 16);
            *(half8*)(xb + row * 256 + (byte ^ ((row & 7) << 4))) = v;
        }
    }
    if (t < BN * 2) {
        int row = t >> 1, hf = t & 1;
        const char* srcp = (const char*)(WT + (size_t)row * 128 + hf * 64);
#pragma unroll
        for (int j = 0; j < 8; ++j) {
            int byte = hf * 128 + j * 16;
            *(half8*)(wb + row * 256 + (byte ^ ((row & 7) << 4))) =
                *(const half8*)(srcp + j * 16);
        }
    }
    __syncthreads();

    constexpr int NCT = BN / 16;
    floatx4 acc[2][NCT];
#pragma unroll
    for (int rt = 0; rt < 2; ++rt)
#pragma unroll
        for (int ct = 0; ct < NCT; ++ct)
#pragma unroll
            for (int r = 0; r < 4; ++r) acc[rt][ct][r] = 0.f;

#pragma unroll
    for (int ks = 0; ks < 4; ++ks) {
        int kbyte = ks * 64 + lg * 16;
        half8 a[2];
#pragma unroll
        for (int rt = 0; rt < 2; ++rt) {
            int r = w * 32 + rt * 16 + lr;
            a[rt] = *(const half8*)(xb + r * 256 + (kbyte ^ ((r & 7) << 4)));
        }
#pragma unroll
        for (int ct = 0; ct < NCT; ++ct) {
            int n = ct * 16 + lr;
            half8 b = *(const half8*)(wb + n * 256 + (kbyte ^ ((n & 7) << 4)));
            acc[0][ct] = __builtin_amdgcn_mfma_f32_16x16x32_f16(a[0], b, acc[0][ct], 0, 0, 0);
            acc[1][ct] = __builtin_amdgcn_mfma_f32_16x16x32_f16(a[1], b, acc[1][ct], 0, 0, 0);
        }
    }

    float bv[NCT];
#pragma unroll
    for (int ct = 0; ct < NCT; ++ct) bv[ct] = BIAS ? bias[ct * 16 + lr] : 0.f;

    // bounce through LDS (reuse Xs) for coalesced f16 stores
    constexpr int ROWB = BN * 2;   // output row bytes
    __syncthreads();
#pragma unroll
    for (int rt = 0; rt < 2; ++rt)
#pragma unroll
        for (int ct = 0; ct < NCT; ++ct)
#pragma unroll
            for (int r = 0; r < 4; ++r) {
                int row = w * 32 + rt * 16 + lg * 4 + r;
                int col = ct * 16 + lr;
                float v = acc[rt][ct][r] + bv[ct];
                if (RELU) v = fmaxf(v, 0.f);
                *(_Float16*)(xb + row * ROWB + ((col * 2) ^ ((row & 7) << 4))) =
                    (_Float16)v;
            }
    __syncthreads();
    {
        int row = t >> 1, hf = t & 1;
        int grow = rowBase + row;
        if (grow < N_NODES) {
            char* dstp = (char*)(Yh + (size_t)grow * BN + hf * (BN / 2));
#pragma unroll
            for (int j = 0; j < BN / 16; ++j) {
                int byte = hf * (ROWB / 2) + j * 16;
                half8 v = *(const half8*)(xb + row * ROWB + (byte ^ ((row & 7) << 4)));
                *(half8*)(dstp + j * 16) = v;
            }
        }
    }
}

// ---------------------------------------------------------------- launch
extern "C" void kernel_launch(void* const* d_in, const int* in_sizes, int n_in,
                              void* d_out, int out_size, void* d_ws, size_t ws_size,
                              hipStream_t stream) {
    const float* feat = (const float*)d_in[0];
    const int*   src  = (const int*)d_in[1];
    const int*   dst  = (const int*)d_in[2];
    const float* W1   = (const float*)d_in[3];
    const float* b1   = (const float*)d_in[4];
    const float* W2a  = (const float*)d_in[5];
    const float* b2a  = (const float*)d_in[6];
    const float* W2b  = (const float*)d_in[7];
    const float* b2b  = (const float*)d_in[8];
    const float* W3   = (const float*)d_in[9];
    const float* b3   = (const float*)d_in[10];
    const float* eps  = (const float*)d_in[11];

    const size_t NH = (size_t)N_NODES * FEAT;
    char* base = (char*)d_ws;
    auto alloc = [&](size_t bytes) {
        char* p = base;
        base += (bytes + 255) & ~(size_t)255;
        return p;
    };
    _Float16* featH = (_Float16*)alloc(NH * 2);
    _Float16* hA    = (_Float16*)alloc(NH * 2);
    _Float16* hB    = (_Float16*)alloc(NH * 2);
    _Float16* WT1   = (_Float16*)alloc(128 * 128 * 2);
    _Float16* WT2a  = (_Float16*)alloc(128 * 128 * 2);
    _Float16* WT2b  = (_Float16*)alloc(128 * 128 * 2);
    _Float16* WT3   = (_Float16*)alloc(128 * 64 * 2);
    uint2* ebuf     = (uint2*)alloc((size_t)NBUCKET * BCAP * 8);
    int* rowptr     = (int*)alloc((N_NODES + 1) * 4);
    int* esrc       = (int*)alloc((size_t)N_EDGES * 4);
    int* gcur       = (int*)alloc(NBUCKET * 4);
    int* bbase      = (int*)alloc(NBUCKET * 4);

    // --- preps
    f32_to_f16_vec<<<2048, 256, 0, stream>>>(feat, featH, (int)(NH / 4));
    wprep<<<64, 256, 0, stream>>>(W1, WT1, 128, 128);
    wprep<<<64, 256, 0, stream>>>(W2a, WT2a, 128, 128);
    wprep<<<64, 256, 0, stream>>>(W2b, WT2b, 128, 128);
    wprep<<<32, 256, 0, stream>>>(W3, WT3, 128, 64);

    // --- bucketed CSR build
    zero_i32<<<(NBUCKET + 255) / 256, 256, 0, stream>>>(gcur, NBUCKET);
    bin_edges<<<(N_EDGES + 4095) / 4096, 512, 0, stream>>>(src, dst, ebuf, gcur);
    scan_buckets<<<1, 512, 0, stream>>>(gcur, bbase, rowptr);
    bucket_csr<<<NBUCKET, 256, 0, stream>>>(ebuf, gcur, bbase, rowptr, esrc);

    const int AGG_GRID = (N_NODES * 64 + 255) / 256;  // 1 wave per node
    const int GEMM_GRID = (N_NODES + 127) / 128;      // 782

    // layer 0: max agg + W1 + relu
    agg_kernel<0, 128, false, false><<<AGG_GRID, 256, 0, stream>>>(
        featH, rowptr, esrc, eps, 0, nullptr, hB, nullptr);
    gemm_mfma<128, true, true><<<GEMM_GRID, 256, 0, stream>>>(hB, WT1, b1, hA);
    // layer 1: sum agg + W2a + relu
    agg_kernel<1, 128, false, false><<<AGG_GRID, 256, 0, stream>>>(
        hA, rowptr, esrc, eps, 1, nullptr, hB, nullptr);
    gemm_mfma<128, true, true><<<GEMM_GRID, 256, 0, stream>>>(hB, WT2a, b2a, hA);
    // layer 2: sum agg + W2b + relu
    agg_kernel<1, 128, false, false><<<AGG_GRID, 256, 0, stream>>>(
        hA, rowptr, esrc, eps, 2, nullptr, hB, nullptr);
    gemm_mfma<128, true, true><<<GEMM_GRID, 256, 0, stream>>>(hB, WT2b, b2b, hA);
    // layer 3 (transform-first): p = hA@W3 (f16, no bias), then mean-agg(64) + b3 -> f32
    gemm_mfma<64, false, false><<<GEMM_GRID, 256, 0, stream>>>(hA, WT3, nullptr, hB);
    agg_kernel<2, 64, true, true><<<AGG_GRID, 256, 0, stream>>>(
        hB, rowptr, esrc, eps, 3, b3, nullptr, (float*)d_out);
}

// Round 6
// 358.825 us; speedup vs baseline: 2.3898x; 1.0802x over previous
//
#include <hip/hip_runtime.h>
#include <math.h>

#define N_NODES 100000
#define N_EDGES 1600000
#define FEAT 128
#define NBUCKET 391   // ceil(N_NODES/256)
#define BCAP 5120     // max edges per 256-node bucket (mean 4096)

typedef __attribute__((ext_vector_type(8))) _Float16 half8;
typedef __attribute__((ext_vector_type(4))) float floatx4;

__device__ inline half8 h8max(half8 a, half8 b) {
    return __builtin_elementwise_max(a, b);   // v_pk_max_f16 x4
}

// ---------------------------------------------------------------- utilities
__global__ __launch_bounds__(256) void zero_i32(int* p, int n) {
    int i = blockIdx.x * 256 + threadIdx.x;
    if (i < n) p[i] = 0;
}

// ---------------------------------------------------------------- bucketed CSR
__global__ __launch_bounds__(512) void bin_edges(const int* __restrict__ src,
                                                 const int* __restrict__ dst,
                                                 uint2* __restrict__ ebuf,
                                                 int* __restrict__ gcur) {
    __shared__ int hist[NBUCKET];
    __shared__ int lbase[NBUCKET];
    __shared__ int cur[NBUCKET];
    __shared__ uint2 tile[4096];

    int t = threadIdx.x;
    int e0 = blockIdx.x * 4096;
    for (int i = t; i < NBUCKET; i += 512) { hist[i] = 0; cur[i] = 0; }
    __syncthreads();

    for (int i = t; i < 4096; i += 512) {
        int e = e0 + i;
        uint2 v; v.x = 0u; v.y = 0xffffffffu;
        if (e < N_EDGES) { v.x = (unsigned)src[e]; v.y = (unsigned)dst[e]; }
        tile[i] = v;
        if (v.y != 0xffffffffu) atomicAdd(&hist[v.y >> 8], 1);
    }
    __syncthreads();

    for (int i = t; i < NBUCKET; i += 512) {
        int c = hist[i];
        lbase[i] = (c > 0) ? atomicAdd(&gcur[i], c) : 0;
    }
    __syncthreads();

    for (int i = t; i < 4096; i += 512) {
        uint2 v = tile[i];
        if (v.y == 0xffffffffu) continue;
        int b = (int)(v.y >> 8);
        int p = lbase[b] + atomicAdd(&cur[b], 1);
        if (p < BCAP) ebuf[(size_t)b * BCAP + p] = v;
    }
}

__global__ __launch_bounds__(512) void scan_buckets(const int* __restrict__ gcur,
                                                    int* __restrict__ bbase,
                                                    int* __restrict__ rowptr) {
    __shared__ int s[512];
    int t = threadIdx.x;
    int v = (t < NBUCKET) ? gcur[t] : 0;
    s[t] = v;
    __syncthreads();
    for (int off = 1; off < 512; off <<= 1) {
        int u = (t >= off) ? s[t - off] : 0;
        __syncthreads();
        s[t] += u;
        __syncthreads();
    }
    if (t < NBUCKET) bbase[t] = s[t] - v;
    if (t == 0) rowptr[N_NODES] = N_EDGES;
}

__global__ __launch_bounds__(256) void bucket_csr(const uint2* __restrict__ ebuf,
                                                  const int* __restrict__ gcur,
                                                  const int* __restrict__ bbase,
                                                  int* __restrict__ rowptr,
                                                  int* __restrict__ esrc) {
    __shared__ int cnt[256];
    __shared__ int off[256];
    __shared__ int astart[256];
    __shared__ int cur[256];

    int b = blockIdx.x, t = threadIdx.x;
    int total = gcur[b]; if (total > BCAP) total = BCAP;
    int base = bbase[b];
    const uint2* eb = ebuf + (size_t)b * BCAP;

    cnt[t] = 0; cur[t] = 0;
    __syncthreads();
    for (int i = t; i < total; i += 256) atomicAdd(&cnt[eb[i].y & 255], 1);
    __syncthreads();

    int v = cnt[t];
    off[t] = v;
    __syncthreads();
    for (int o = 1; o < 256; o <<= 1) {
        int u = (t >= o) ? off[t - o] : 0;
        __syncthreads();
        off[t] += u;
        __syncthreads();
    }
    int excl = off[t] - v;
    int node = (b << 8) + t;
    if (node < N_NODES) rowptr[node] = base + excl;
    astart[t] = base + excl;
    __syncthreads();

    for (int i = t; i < total; i += 256) {
        uint2 e = eb[i];
        int ln = (int)(e.y & 255);
        int p = astart[ln] + atomicAdd(&cur[ln], 1);
        esrc[p] = (int)e.x;
    }
}

// ---------------------------------------------------------------- conversions
__global__ __launch_bounds__(256) void f32_to_f16_vec(const float* __restrict__ in,
                                                      _Float16* __restrict__ out,
                                                      int n4) {
    int i = blockIdx.x * 256 + threadIdx.x;
    int stride = gridDim.x * 256;
    for (; i < n4; i += stride) {
        float4 v = ((const float4*)in)[i];
        union { uint2 u; _Float16 h[4]; } p;
        p.h[0] = (_Float16)v.x; p.h[1] = (_Float16)v.y;
        p.h[2] = (_Float16)v.z; p.h[3] = (_Float16)v.w;
        *(uint2*)(out + 4 * (size_t)i) = p.u;
    }
}

// W f32 [K][N] -> WT f16 [N][K]
__global__ __launch_bounds__(256) void wprep(const float* __restrict__ W,
                                             _Float16* __restrict__ WT,
                                             int K, int N) {
    int idx = blockIdx.x * 256 + threadIdx.x;
    if (idx < K * N) {
        int n = idx / K, k = idx % K;
        WT[idx] = (_Float16)W[k * N + n];
    }
}

// ---------------------------------------------------------------- aggregation
// One wave per node; LPE lanes per edge-row (16B each), NG edges per wave-load.
// Packed f16 accumulation (pk_max / pk_add); f32 only in the 8-elem epilogue.
template <int MODE, int D, bool OUTF32, bool BIAS>
__global__ __launch_bounds__(256) void agg_kernel(const _Float16* __restrict__ h,
                                                  const int* __restrict__ rowptr,
                                                  const int* __restrict__ esrc,
                                                  const float* __restrict__ eps,
                                                  int ei,
                                                  const float* __restrict__ bias,
                                                  _Float16* __restrict__ outH,
                                                  float* __restrict__ outF) {
    constexpr int LPE = D / 8;
    constexpr int NG = 64 / LPE;
    int node = (int)((blockIdx.x * 256 + threadIdx.x) >> 6);
    if (node >= N_NODES) return;
    int l = threadIdx.x & 63;
    int grp = l / LPE, sl = l & (LPE - 1);
    int beg = rowptr[node], end = rowptr[node + 1];
    int deg = end - beg;

    _Float16 init = (MODE == 0) ? (_Float16)(-65504.0f) : (_Float16)(0.0f);
    half8 acc = {init, init, init, init, init, init, init, init};

    int e = beg;
    for (; e + 2 * NG <= end; e += 2 * NG) {
        int s0 = esrc[e + grp];
        int s1 = esrc[e + NG + grp];
        half8 v0 = *(const half8*)(h + (size_t)s0 * D + sl * 8);
        half8 v1 = *(const half8*)(h + (size_t)s1 * D + sl * 8);
        if (MODE == 0) acc = h8max(acc, h8max(v0, v1));
        else           acc += v0 + v1;
    }
    for (; e < end; e += NG) {
        int ee = e + grp;
        if (ee < end) {
            int s = esrc[ee];
            half8 v = *(const half8*)(h + (size_t)s * D + sl * 8);
            if (MODE == 0) acc = h8max(acc, v);
            else           acc += v;
        }
    }

    // combine edge groups (packed words)
    union HU { half8 h; int w[4]; };
    HU U; U.h = acc;
#pragma unroll
    for (int m = LPE; m < 64; m <<= 1) {
        HU V;
#pragma unroll
        for (int k = 0; k < 4; ++k) V.w[k] = __shfl_xor(U.w[k], m, 64);
        if (MODE == 0) U.h = h8max(U.h, V.h);
        else           U.h = U.h + V.h;
    }

    if (grp != 0) return;

    float a[8];
#pragma unroll
    for (int i = 0; i < 8; ++i) a[i] = (float)U.h[i];
    if (MODE == 0 && deg == 0) {
#pragma unroll
        for (int i = 0; i < 8; ++i) a[i] = 0.f;
    }
    if (MODE == 2) {
        float inv = 1.f / (float)(deg > 0 ? deg : 1);
#pragma unroll
        for (int i = 0; i < 8; ++i) a[i] *= inv;
    }
    float sc = 1.f + eps[ei];
    half8 self = *(const half8*)(h + (size_t)node * D + sl * 8);
    float o[8];
#pragma unroll
    for (int i = 0; i < 8; ++i) o[i] = fmaf(sc, (float)self[i], a[i]);

    if (OUTF32) {
#pragma unroll
        for (int i = 0; i < 8; ++i)
            if (BIAS) o[i] += bias[sl * 8 + i];
        float4* dstp = (float4*)(outF + (size_t)node * D + sl * 8);
        dstp[0] = make_float4(o[0], o[1], o[2], o[3]);
        dstp[1] = make_float4(o[4], o[5], o[6], o[7]);
    } else {
        half8 ov;
#pragma unroll
        for (int i = 0; i < 8; ++i) ov[i] = (_Float16)o[i];
        *(half8*)(outH + (size_t)node * D + sl * 8) = ov;
    }
}

// ---------------------------------------------------------------- MFMA GEMM
// Y = act(X[M][128] @ W[128][BN] (+bias)); X f16, WT f16 [BN][128]
// BM=64 rows/block, 4 waves x 16 rows. LDS 48KB (BN=128) -> 3 blocks/CU.
template <int BN, bool RELU, bool BIAS>
__global__ __launch_bounds__(256) void gemm_mfma(const _Float16* __restrict__ X,
                                                 const _Float16* __restrict__ WT,
                                                 const float* __restrict__ bias,
                                                 _Float16* __restrict__ Yh) {
    __shared__ _Float16 Xs[64 * 128];   // 16 KB
    __shared__ _Float16 Ws[BN * 128];   // 32 KB (BN=128) / 16 KB (BN=64)
    char* xb = (char*)Xs;
    char* wb = (char*)Ws;

    int t = threadIdx.x;
    int l = t & 63, w = t >> 6;
    int lr = l & 15, lg = l >> 4;
    int rowBase = blockIdx.x * 64;

    // stage X tile: 64 rows x 256B; thread t covers 64B of row t>>2
    {
        int row = t >> 2, q = t & 3;
        int grow = rowBase + row;
        const char* srcp = (const char*)(X + (size_t)grow * 128) + q * 64;
#pragma unroll
        for (int j = 0; j < 4; ++j) {
            int byte = q * 64 + j * 16;
            half8 v = {};
            if (grow < N_NODES) v = *(const half8*)(srcp + j * 16);
            *(half8*)(xb + row * 256 + (byte ^ ((row & 7) << 4))) = v;
        }
    }
    // stage W tile: BN rows x 256B, 4KB per pass
    {
#pragma unroll
        for (int p = 0; p < BN / 16; ++p) {
            int idx = p * 4096 + t * 16;
            int row = idx >> 8, byte = idx & 255;
            *(half8*)(wb + row * 256 + (byte ^ ((row & 7) << 4))) =
                *(const half8*)((const char*)WT + idx);
        }
    }
    __syncthreads();

    constexpr int NCT = BN / 16;
    floatx4 acc[NCT];
#pragma unroll
    for (int ct = 0; ct < NCT; ++ct)
#pragma unroll
        for (int r = 0; r < 4; ++r) acc[ct][r] = 0.f;

#pragma unroll
    for (int ks = 0; ks < 4; ++ks) {
        int kbyte = ks * 64 + lg * 16;
        int r = w * 16 + lr;
        half8 a = *(const half8*)(xb + r * 256 + (kbyte ^ ((r & 7) << 4)));
#pragma unroll
        for (int ct = 0; ct < NCT; ++ct) {
            int n = ct * 16 + lr;
            half8 b = *(const half8*)(wb + n * 256 + (kbyte ^ ((n & 7) << 4)));
            acc[ct] = __builtin_amdgcn_mfma_f32_16x16x32_f16(a, b, acc[ct], 0, 0, 0);
        }
    }

    float bv[NCT];
#pragma unroll
    for (int ct = 0; ct < NCT; ++ct) bv[ct] = BIAS ? bias[ct * 16 + lr] : 0.f;

    // bounce through LDS (reuse Xs) for coalesced f16 stores
    constexpr int ROWB = BN * 2;
    __syncthreads();
#pragma unroll
    for (int ct = 0; ct < NCT; ++ct)
#pragma unroll
        for (int r = 0; r < 4; ++r) {
            int row = w * 16 + lg * 4 + r;
            int col = ct * 16 + lr;
            float v = acc[ct][r] + bv[ct];
            if (RELU) v = fmaxf(v, 0.f);
            *(_Float16*)(xb + row * ROWB + ((col * 2) ^ ((row & 7) << 4))) =
                (_Float16)v;
        }
    __syncthreads();
    {
        int row = t >> 2, q = t & 3;
        int grow = rowBase + row;
        if (grow < N_NODES) {
            char* dstp = (char*)(Yh + (size_t)grow * BN) + q * (ROWB / 4);
#pragma unroll
            for (int j = 0; j < ROWB / 64; ++j) {
                int byte = q * (ROWB / 4) + j * 16;
                half8 v = *(const half8*)(xb + row * ROWB + (byte ^ ((row & 7) << 4)));
                *(half8*)(dstp + j * 16) = v;
            }
        }
    }
}

// ---------------------------------------------------------------- launch
extern "C" void kernel_launch(void* const* d_in, const int* in_sizes, int n_in,
                              void* d_out, int out_size, void* d_ws, size_t ws_size,
                              hipStream_t stream) {
    const float* feat = (const float*)d_in[0];
    const int*   src  = (const int*)d_in[1];
    const int*   dst  = (const int*)d_in[2];
    const float* W1   = (const float*)d_in[3];
    const float* b1   = (const float*)d_in[4];
    const float* W2a  = (const float*)d_in[5];
    const float* b2a  = (const float*)d_in[6];
    const float* W2b  = (const float*)d_in[7];
    const float* b2b  = (const float*)d_in[8];
    const float* W3   = (const float*)d_in[9];
    const float* b3   = (const float*)d_in[10];
    const float* eps  = (const float*)d_in[11];

    const size_t NH = (size_t)N_NODES * FEAT;
    char* base = (char*)d_ws;
    auto alloc = [&](size_t bytes) {
        char* p = base;
        base += (bytes + 255) & ~(size_t)255;
        return p;
    };
    _Float16* featH = (_Float16*)alloc(NH * 2);
    _Float16* hA    = (_Float16*)alloc(NH * 2);
    _Float16* hB    = (_Float16*)alloc(NH * 2);
    _Float16* WT1   = (_Float16*)alloc(128 * 128 * 2);
    _Float16* WT2a  = (_Float16*)alloc(128 * 128 * 2);
    _Float16* WT2b  = (_Float16*)alloc(128 * 128 * 2);
    _Float16* WT3   = (_Float16*)alloc(128 * 64 * 2);
    uint2* ebuf     = (uint2*)alloc((size_t)NBUCKET * BCAP * 8);
    int* rowptr     = (int*)alloc((N_NODES + 1) * 4);
    int* esrc       = (int*)alloc((size_t)N_EDGES * 4);
    int* gcur       = (int*)alloc(NBUCKET * 4);
    int* bbase      = (int*)alloc(NBUCKET * 4);

    // --- preps
    f32_to_f16_vec<<<2048, 256, 0, stream>>>(feat, featH, (int)(NH / 4));
    wprep<<<64, 256, 0, stream>>>(W1, WT1, 128, 128);
    wprep<<<64, 256, 0, stream>>>(W2a, WT2a, 128, 128);
    wprep<<<64, 256, 0, stream>>>(W2b, WT2b, 128, 128);
    wprep<<<32, 256, 0, stream>>>(W3, WT3, 128, 64);

    // --- bucketed CSR build
    zero_i32<<<(NBUCKET + 255) / 256, 256, 0, stream>>>(gcur, NBUCKET);
    bin_edges<<<(N_EDGES + 4095) / 4096, 512, 0, stream>>>(src, dst, ebuf, gcur);
    scan_buckets<<<1, 512, 0, stream>>>(gcur, bbase, rowptr);
    bucket_csr<<<NBUCKET, 256, 0, stream>>>(ebuf, gcur, bbase, rowptr, esrc);

    const int AGG_GRID = (N_NODES * 64 + 255) / 256;   // 1 wave per node
    const int GEMM_GRID = (N_NODES + 63) / 64;         // 1563

    // layer 0: max agg + W1 + relu
    agg_kernel<0, 128, false, false><<<AGG_GRID, 256, 0, stream>>>(
        featH, rowptr, esrc, eps, 0, nullptr, hB, nullptr);
    gemm_mfma<128, true, true><<<GEMM_GRID, 256, 0, stream>>>(hB, WT1, b1, hA);
    // layer 1: sum agg + W2a + relu
    agg_kernel<1, 128, false, false><<<AGG_GRID, 256, 0, stream>>>(
        hA, rowptr, esrc, eps, 1, nullptr, hB, nullptr);
    gemm_mfma<128, true, true><<<GEMM_GRID, 256, 0, stream>>>(hB, WT2a, b2a, hA);
    // layer 2: sum agg + W2b + relu
    agg_kernel<1, 128, false, false><<<AGG_GRID, 256, 0, stream>>>(
        hA, rowptr, esrc, eps, 2, nullptr, hB, nullptr);
    gemm_mfma<128, true, true><<<GEMM_GRID, 256, 0, stream>>>(hB, WT2b, b2b, hA);
    // layer 3 (transform-first): p = hA@W3 (f16), then mean-agg(64) + b3 -> f32
    gemm_mfma<64, false, false><<<GEMM_GRID, 256, 0, stream>>>(hA, WT3, nullptr, hB);
    agg_kernel<2, 64, true, true><<<AGG_GRID, 256, 0, stream>>>(
        hB, rowptr, esrc, eps, 3, b3, nullptr, (float*)d_out);
}

// Round 7
// 342.050 us; speedup vs baseline: 2.5070x; 1.0490x over previous
//
#include <hip/hip_runtime.h>
#include <math.h>

#define N_NODES 100000
#define N_EDGES 1600000
#define FEAT 128
#define NBUCKET 391   // ceil(N_NODES/256)
#define BCAP 5120     // max edges per 256-node bucket (mean 4096)

typedef __attribute__((ext_vector_type(8))) _Float16 half8;
typedef __attribute__((ext_vector_type(4))) float floatx4;

__device__ inline half8 h8max(half8 a, half8 b) {
    return __builtin_elementwise_max(a, b);   // v_pk_max_f16 x4
}

// ---------------------------------------------------------------- utilities
__global__ __launch_bounds__(256) void zero_i32(int* p, int n) {
    int i = blockIdx.x * 256 + threadIdx.x;
    if (i < n) p[i] = 0;
}

// ---------------------------------------------------------------- bucketed CSR
__global__ __launch_bounds__(512) void bin_edges(const int* __restrict__ src,
                                                 const int* __restrict__ dst,
                                                 uint2* __restrict__ ebuf,
                                                 int* __restrict__ gcur) {
    __shared__ int hist[NBUCKET];
    __shared__ int lbase[NBUCKET];
    __shared__ int cur[NBUCKET];
    __shared__ uint2 tile[4096];

    int t = threadIdx.x;
    int e0 = blockIdx.x * 4096;
    for (int i = t; i < NBUCKET; i += 512) { hist[i] = 0; cur[i] = 0; }
    __syncthreads();

    for (int i = t; i < 4096; i += 512) {
        int e = e0 + i;
        uint2 v; v.x = 0u; v.y = 0xffffffffu;
        if (e < N_EDGES) { v.x = (unsigned)src[e]; v.y = (unsigned)dst[e]; }
        tile[i] = v;
        if (v.y != 0xffffffffu) atomicAdd(&hist[v.y >> 8], 1);
    }
    __syncthreads();

    for (int i = t; i < NBUCKET; i += 512) {
        int c = hist[i];
        lbase[i] = (c > 0) ? atomicAdd(&gcur[i], c) : 0;
    }
    __syncthreads();

    for (int i = t; i < 4096; i += 512) {
        uint2 v = tile[i];
        if (v.y == 0xffffffffu) continue;
        int b = (int)(v.y >> 8);
        int p = lbase[b] + atomicAdd(&cur[b], 1);
        if (p < BCAP) ebuf[(size_t)b * BCAP + p] = v;
    }
}

__global__ __launch_bounds__(512) void scan_buckets(const int* __restrict__ gcur,
                                                    int* __restrict__ bbase,
                                                    int* __restrict__ rowptr) {
    __shared__ int s[512];
    int t = threadIdx.x;
    int v = (t < NBUCKET) ? gcur[t] : 0;
    s[t] = v;
    __syncthreads();
    for (int off = 1; off < 512; off <<= 1) {
        int u = (t >= off) ? s[t - off] : 0;
        __syncthreads();
        s[t] += u;
        __syncthreads();
    }
    if (t < NBUCKET) bbase[t] = s[t] - v;
    if (t == 0) rowptr[N_NODES] = N_EDGES;
}

__global__ __launch_bounds__(256) void bucket_csr(const uint2* __restrict__ ebuf,
                                                  const int* __restrict__ gcur,
                                                  const int* __restrict__ bbase,
                                                  int* __restrict__ rowptr,
                                                  int* __restrict__ esrc) {
    __shared__ int cnt[256];
    __shared__ int off[256];
    __shared__ int astart[256];
    __shared__ int cur[256];

    int b = blockIdx.x, t = threadIdx.x;
    int total = gcur[b]; if (total > BCAP) total = BCAP;
    int base = bbase[b];
    const uint2* eb = ebuf + (size_t)b * BCAP;

    cnt[t] = 0; cur[t] = 0;
    __syncthreads();
    for (int i = t; i < total; i += 256) atomicAdd(&cnt[eb[i].y & 255], 1);
    __syncthreads();

    int v = cnt[t];
    off[t] = v;
    __syncthreads();
    for (int o = 1; o < 256; o <<= 1) {
        int u = (t >= o) ? off[t - o] : 0;
        __syncthreads();
        off[t] += u;
        __syncthreads();
    }
    int excl = off[t] - v;
    int node = (b << 8) + t;
    if (node < N_NODES) rowptr[node] = base + excl;
    astart[t] = base + excl;
    __syncthreads();

    for (int i = t; i < total; i += 256) {
        uint2 e = eb[i];
        int ln = (int)(e.y & 255);
        int p = astart[ln] + atomicAdd(&cur[ln], 1);
        esrc[p] = (int)e.x;
    }
}

// ---------------------------------------------------------------- conversions
__global__ __launch_bounds__(256) void f32_to_f16_vec(const float* __restrict__ in,
                                                      _Float16* __restrict__ out,
                                                      int n4) {
    int i = blockIdx.x * 256 + threadIdx.x;
    int stride = gridDim.x * 256;
    for (; i < n4; i += stride) {
        float4 v = ((const float4*)in)[i];
        union { uint2 u; _Float16 h[4]; } p;
        p.h[0] = (_Float16)v.x; p.h[1] = (_Float16)v.y;
        p.h[2] = (_Float16)v.z; p.h[3] = (_Float16)v.w;
        *(uint2*)(out + 4 * (size_t)i) = p.u;
    }
}

// W f32 [K][N] -> WT f16 [N][K]
__global__ __launch_bounds__(256) void wprep(const float* __restrict__ W,
                                             _Float16* __restrict__ WT,
                                             int K, int N) {
    int idx = blockIdx.x * 256 + threadIdx.x;
    if (idx < K * N) {
        int n = idx / K, k = idx % K;
        WT[idx] = (_Float16)W[k * N + n];
    }
}

// ---------------------------------------------------------------- aggregation
// Each LPE-lane group owns ONE node (NPW nodes per wave). Masked chunks of 8
// edges -> 8 independent row-loads in flight per lane. Packed f16 accumulate.
template <int MODE, int D, bool OUTF32, bool BIAS>
__global__ __launch_bounds__(256) void agg_kernel(const _Float16* __restrict__ h,
                                                  const int* __restrict__ rowptr,
                                                  const int* __restrict__ esrc,
                                                  const float* __restrict__ eps,
                                                  int ei,
                                                  const float* __restrict__ bias,
                                                  _Float16* __restrict__ outH,
                                                  float* __restrict__ outF) {
    constexpr int LPE = D / 8;     // lanes per node-row (16B each)
    constexpr int NPW = 64 / LPE;  // nodes per wave
    int wid = (int)((blockIdx.x * 256 + threadIdx.x) >> 6);
    int l = threadIdx.x & 63;
    int grp = l / LPE, sl = l % LPE;
    int node = wid * NPW + grp;
    if (node >= N_NODES) return;
    int beg = rowptr[node], end = rowptr[node + 1];
    int deg = end - beg;

    const _Float16 NEUT = (MODE == 0) ? (_Float16)(-65504.0f) : (_Float16)(0.0f);
    half8 neut8 = {NEUT, NEUT, NEUT, NEUT, NEUT, NEUT, NEUT, NEUT};
    half8 acc = neut8;

    for (int e = beg; e < end; e += 8) {
        half8 v[8];
#pragma unroll
        for (int j = 0; j < 8; ++j) {
            int ee = e + j;
            int s = esrc[ee < end ? ee : end - 1];
            v[j] = *(const half8*)(h + (size_t)s * D + sl * 8);
        }
#pragma unroll
        for (int j = 0; j < 8; ++j)
            if (e + j >= end) v[j] = neut8;
        if (MODE == 0) {
            half8 m01 = h8max(v[0], v[1]), m23 = h8max(v[2], v[3]);
            half8 m45 = h8max(v[4], v[5]), m67 = h8max(v[6], v[7]);
            acc = h8max(acc, h8max(h8max(m01, m23), h8max(m45, m67)));
        } else {
            half8 s01 = v[0] + v[1], s23 = v[2] + v[3];
            half8 s45 = v[4] + v[5], s67 = v[6] + v[7];
            acc += (s01 + s23) + (s45 + s67);
        }
    }

    float a[8];
#pragma unroll
    for (int i = 0; i < 8; ++i) a[i] = (float)acc[i];
    if (MODE == 0 && deg == 0) {
#pragma unroll
        for (int i = 0; i < 8; ++i) a[i] = 0.f;
    }
    if (MODE == 2) {
        float inv = 1.f / (float)(deg > 0 ? deg : 1);
#pragma unroll
        for (int i = 0; i < 8; ++i) a[i] *= inv;
    }
    float sc = 1.f + eps[ei];
    half8 self = *(const half8*)(h + (size_t)node * D + sl * 8);
    float o[8];
#pragma unroll
    for (int i = 0; i < 8; ++i) o[i] = fmaf(sc, (float)self[i], a[i]);

    if (OUTF32) {
#pragma unroll
        for (int i = 0; i < 8; ++i)
            if (BIAS) o[i] += bias[sl * 8 + i];
        float4* dstp = (float4*)(outF + (size_t)node * D + sl * 8);
        dstp[0] = make_float4(o[0], o[1], o[2], o[3]);
        dstp[1] = make_float4(o[4], o[5], o[6], o[7]);
    } else {
        half8 ov;
#pragma unroll
        for (int i = 0; i < 8; ++i) ov[i] = (_Float16)o[i];
        *(half8*)(outH + (size_t)node * D + sl * 8) = ov;
    }
}

// ---------------------------------------------------------------- MFMA GEMM
// Y = act(X[M][128] @ W[128][BN] (+bias)); X f16, WT f16 [BN][128]
// BM=64 rows/block, 4 waves x 16 rows.
template <int BN, bool RELU, bool BIAS>
__global__ __launch_bounds__(256) void gemm_mfma(const _Float16* __restrict__ X,
                                                 const _Float16* __restrict__ WT,
                                                 const float* __restrict__ bias,
                                                 _Float16* __restrict__ Yh) {
    __shared__ _Float16 Xs[64 * 128];   // 16 KB
    __shared__ _Float16 Ws[BN * 128];   // 32 KB (BN=128) / 16 KB (BN=64)
    char* xb = (char*)Xs;
    char* wb = (char*)Ws;

    int t = threadIdx.x;
    int l = t & 63, w = t >> 6;
    int lr = l & 15, lg = l >> 4;
    int rowBase = blockIdx.x * 64;

    // stage X tile: 64 rows x 256B; thread t covers 64B of row t>>2
    {
        int row = t >> 2, q = t & 3;
        int grow = rowBase + row;
        const char* srcp = (const char*)(X + (size_t)grow * 128) + q * 64;
#pragma unroll
        for (int j = 0; j < 4; ++j) {
            int byte = q * 64 + j * 16;
            half8 v = {};
            if (grow < N_NODES) v = *(const half8*)(srcp + j * 16);
            *(half8*)(xb + row * 256 + (byte ^ ((row & 7) << 4))) = v;
        }
    }
    // stage W tile: BN rows x 256B, 4KB per pass
    {
#pragma unroll
        for (int p = 0; p < BN / 16; ++p) {
            int idx = p * 4096 + t * 16;
            int row = idx >> 8, byte = idx & 255;
            *(half8*)(wb + row * 256 + (byte ^ ((row & 7) << 4))) =
                *(const half8*)((const char*)WT + idx);
        }
    }
    __syncthreads();

    constexpr int NCT = BN / 16;
    floatx4 acc[NCT];
#pragma unroll
    for (int ct = 0; ct < NCT; ++ct)
#pragma unroll
        for (int r = 0; r < 4; ++r) acc[ct][r] = 0.f;

#pragma unroll
    for (int ks = 0; ks < 4; ++ks) {
        int kbyte = ks * 64 + lg * 16;
        int r = w * 16 + lr;
        half8 a = *(const half8*)(xb + r * 256 + (kbyte ^ ((r & 7) << 4)));
#pragma unroll
        for (int ct = 0; ct < NCT; ++ct) {
            int n = ct * 16 + lr;
            half8 b = *(const half8*)(wb + n * 256 + (kbyte ^ ((n & 7) << 4)));
            acc[ct] = __builtin_amdgcn_mfma_f32_16x16x32_f16(a, b, acc[ct], 0, 0, 0);
        }
    }

    float bv[NCT];
#pragma unroll
    for (int ct = 0; ct < NCT; ++ct) bv[ct] = BIAS ? bias[ct * 16 + lr] : 0.f;

    // bounce through LDS (reuse Xs) for coalesced f16 stores
    constexpr int ROWB = BN * 2;
    __syncthreads();
#pragma unroll
    for (int ct = 0; ct < NCT; ++ct)
#pragma unroll
        for (int r = 0; r < 4; ++r) {
            int row = w * 16 + lg * 4 + r;
            int col = ct * 16 + lr;
            float v = acc[ct][r] + bv[ct];
            if (RELU) v = fmaxf(v, 0.f);
            *(_Float16*)(xb + row * ROWB + ((col * 2) ^ ((row & 7) << 4))) =
                (_Float16)v;
        }
    __syncthreads();
    {
        int row = t >> 2, q = t & 3;
        int grow = rowBase + row;
        if (grow < N_NODES) {
            char* dstp = (char*)(Yh + (size_t)grow * BN) + q * (ROWB / 4);
#pragma unroll
            for (int j = 0; j < ROWB / 64; ++j) {
                int byte = q * (ROWB / 4) + j * 16;
                half8 v = *(const half8*)(xb + row * ROWB + (byte ^ ((row & 7) << 4)));
                *(half8*)(dstp + j * 16) = v;
            }
        }
    }
}

// ---------------------------------------------------------------- launch
extern "C" void kernel_launch(void* const* d_in, const int* in_sizes, int n_in,
                              void* d_out, int out_size, void* d_ws, size_t ws_size,
                              hipStream_t stream) {
    const float* feat = (const float*)d_in[0];
    const int*   src  = (const int*)d_in[1];
    const int*   dst  = (const int*)d_in[2];
    const float* W1   = (const float*)d_in[3];
    const float* b1   = (const float*)d_in[4];
    const float* W2a  = (const float*)d_in[5];
    const float* b2a  = (const float*)d_in[6];
    const float* W2b  = (const float*)d_in[7];
    const float* b2b  = (const float*)d_in[8];
    const float* W3   = (const float*)d_in[9];
    const float* b3   = (const float*)d_in[10];
    const float* eps  = (const float*)d_in[11];

    const size_t NH = (size_t)N_NODES * FEAT;
    char* base = (char*)d_ws;
    auto alloc = [&](size_t bytes) {
        char* p = base;
        base += (bytes + 255) & ~(size_t)255;
        return p;
    };
    _Float16* featH = (_Float16*)alloc(NH * 2);
    _Float16* hA    = (_Float16*)alloc(NH * 2);
    _Float16* hB    = (_Float16*)alloc(NH * 2);
    _Float16* WT1   = (_Float16*)alloc(128 * 128 * 2);
    _Float16* WT2a  = (_Float16*)alloc(128 * 128 * 2);
    _Float16* WT2b  = (_Float16*)alloc(128 * 128 * 2);
    _Float16* WT3   = (_Float16*)alloc(128 * 64 * 2);
    uint2* ebuf     = (uint2*)alloc((size_t)NBUCKET * BCAP * 8);
    int* rowptr     = (int*)alloc((N_NODES + 1) * 4);
    int* esrc       = (int*)alloc((size_t)N_EDGES * 4);
    int* gcur       = (int*)alloc(NBUCKET * 4);
    int* bbase      = (int*)alloc(NBUCKET * 4);

    // --- preps
    f32_to_f16_vec<<<2048, 256, 0, stream>>>(feat, featH, (int)(NH / 4));
    wprep<<<64, 256, 0, stream>>>(W1, WT1, 128, 128);
    wprep<<<64, 256, 0, stream>>>(W2a, WT2a, 128, 128);
    wprep<<<64, 256, 0, stream>>>(W2b, WT2b, 128, 128);
    wprep<<<32, 256, 0, stream>>>(W3, WT3, 128, 64);

    // --- bucketed CSR build
    zero_i32<<<(NBUCKET + 255) / 256, 256, 0, stream>>>(gcur, NBUCKET);
    bin_edges<<<(N_EDGES + 4095) / 4096, 512, 0, stream>>>(src, dst, ebuf, gcur);
    scan_buckets<<<1, 512, 0, stream>>>(gcur, bbase, rowptr);
    bucket_csr<<<NBUCKET, 256, 0, stream>>>(ebuf, gcur, bbase, rowptr, esrc);

    // agg grids: nodes per block = 4 waves * NPW
    const int AGG128_GRID = (N_NODES + 15) / 16;   // NPW=4  -> 16 nodes/block
    const int AGG64_GRID  = (N_NODES + 31) / 32;   // NPW=8  -> 32 nodes/block
    const int GEMM_GRID = (N_NODES + 63) / 64;     // 1563

    // layer 0: max agg + W1 + relu
    agg_kernel<0, 128, false, false><<<AGG128_GRID, 256, 0, stream>>>(
        featH, rowptr, esrc, eps, 0, nullptr, hB, nullptr);
    gemm_mfma<128, true, true><<<GEMM_GRID, 256, 0, stream>>>(hB, WT1, b1, hA);
    // layer 1: sum agg + W2a + relu
    agg_kernel<1, 128, false, false><<<AGG128_GRID, 256, 0, stream>>>(
        hA, rowptr, esrc, eps, 1, nullptr, hB, nullptr);
    gemm_mfma<128, true, true><<<GEMM_GRID, 256, 0, stream>>>(hB, WT2a, b2a, hA);
    // layer 2: sum agg + W2b + relu
    agg_kernel<1, 128, false, false><<<AGG128_GRID, 256, 0, stream>>>(
        hA, rowptr, esrc, eps, 2, nullptr, hB, nullptr);
    gemm_mfma<128, true, true><<<GEMM_GRID, 256, 0, stream>>>(hB, WT2b, b2b, hA);
    // layer 3 (transform-first): p = hA@W3 (f16), then mean-agg(64) + b3 -> f32
    gemm_mfma<64, false, false><<<GEMM_GRID, 256, 0, stream>>>(hA, WT3, nullptr, hB);
    agg_kernel<2, 64, true, true><<<AGG64_GRID, 256, 0, stream>>>(
        hB, rowptr, esrc, eps, 3, b3, nullptr, (float*)d_out);
}

// Round 8
// 329.385 us; speedup vs baseline: 2.6034x; 1.0385x over previous
//
#include <hip/hip_runtime.h>
#include <math.h>

#define N_NODES 100000
#define N_EDGES 1600000
#define FEAT 128
#define NBUCKET 391   // ceil(N_NODES/256)
#define BCAP 5120     // max edges per 256-node bucket (mean 4096)

typedef __attribute__((ext_vector_type(8))) _Float16 half8;
typedef __attribute__((ext_vector_type(4))) float floatx4;

__device__ inline half8 h8max(half8 a, half8 b) {
    return __builtin_elementwise_max(a, b);   // v_pk_max_f16 x4
}

// ---------------------------------------------------------------- utilities
__global__ __launch_bounds__(256) void zero_i32(int* p, int n) {
    int i = blockIdx.x * 256 + threadIdx.x;
    if (i < n) p[i] = 0;
}

// ---------------------------------------------------------------- bucketed CSR
__global__ __launch_bounds__(512) void bin_edges(const int* __restrict__ src,
                                                 const int* __restrict__ dst,
                                                 uint2* __restrict__ ebuf,
                                                 int* __restrict__ gcur) {
    __shared__ int hist[NBUCKET];
    __shared__ int lbase[NBUCKET];
    __shared__ int cur[NBUCKET];
    __shared__ uint2 tile[4096];

    int t = threadIdx.x;
    int e0 = blockIdx.x * 4096;
    for (int i = t; i < NBUCKET; i += 512) { hist[i] = 0; cur[i] = 0; }
    __syncthreads();

    for (int i = t; i < 4096; i += 512) {
        int e = e0 + i;
        uint2 v; v.x = 0u; v.y = 0xffffffffu;
        if (e < N_EDGES) { v.x = (unsigned)src[e]; v.y = (unsigned)dst[e]; }
        tile[i] = v;
        if (v.y != 0xffffffffu) atomicAdd(&hist[v.y >> 8], 1);
    }
    __syncthreads();

    for (int i = t; i < NBUCKET; i += 512) {
        int c = hist[i];
        lbase[i] = (c > 0) ? atomicAdd(&gcur[i], c) : 0;
    }
    __syncthreads();

    for (int i = t; i < 4096; i += 512) {
        uint2 v = tile[i];
        if (v.y == 0xffffffffu) continue;
        int b = (int)(v.y >> 8);
        int p = lbase[b] + atomicAdd(&cur[b], 1);
        if (p < BCAP) ebuf[(size_t)b * BCAP + p] = v;
    }
}

__global__ __launch_bounds__(512) void scan_buckets(const int* __restrict__ gcur,
                                                    int* __restrict__ bbase,
                                                    int* __restrict__ rowptr) {
    __shared__ int s[512];
    int t = threadIdx.x;
    int v = (t < NBUCKET) ? gcur[t] : 0;
    s[t] = v;
    __syncthreads();
    for (int off = 1; off < 512; off <<= 1) {
        int u = (t >= off) ? s[t - off] : 0;
        __syncthreads();
        s[t] += u;
        __syncthreads();
    }
    if (t < NBUCKET) bbase[t] = s[t] - v;
    if (t == 0) rowptr[N_NODES] = N_EDGES;
}

__global__ __launch_bounds__(256) void bucket_csr(const uint2* __restrict__ ebuf,
                                                  const int* __restrict__ gcur,
                                                  const int* __restrict__ bbase,
                                                  int* __restrict__ rowptr,
                                                  int* __restrict__ esrc) {
    __shared__ int cnt[256];
    __shared__ int off[256];
    __shared__ int astart[256];
    __shared__ int cur[256];

    int b = blockIdx.x, t = threadIdx.x;
    int total = gcur[b]; if (total > BCAP) total = BCAP;
    int base = bbase[b];
    const uint2* eb = ebuf + (size_t)b * BCAP;

    cnt[t] = 0; cur[t] = 0;
    __syncthreads();
    for (int i = t; i < total; i += 256) atomicAdd(&cnt[eb[i].y & 255], 1);
    __syncthreads();

    int v = cnt[t];
    off[t] = v;
    __syncthreads();
    for (int o = 1; o < 256; o <<= 1) {
        int u = (t >= o) ? off[t - o] : 0;
        __syncthreads();
        off[t] += u;
        __syncthreads();
    }
    int excl = off[t] - v;
    int node = (b << 8) + t;
    if (node < N_NODES) rowptr[node] = base + excl;
    astart[t] = base + excl;
    __syncthreads();

    for (int i = t; i < total; i += 256) {
        uint2 e = eb[i];
        int ln = (int)(e.y & 255);
        int p = astart[ln] + atomicAdd(&cur[ln], 1);
        esrc[p] = (int)e.x;
    }
}

// ---------------------------------------------------------------- conversions
__global__ __launch_bounds__(256) void f32_to_f16_vec(const float* __restrict__ in,
                                                      _Float16* __restrict__ out,
                                                      int n4) {
    int i = blockIdx.x * 256 + threadIdx.x;
    int stride = gridDim.x * 256;
    for (; i < n4; i += stride) {
        float4 v = ((const float4*)in)[i];
        union { uint2 u; _Float16 h[4]; } p;
        p.h[0] = (_Float16)v.x; p.h[1] = (_Float16)v.y;
        p.h[2] = (_Float16)v.z; p.h[3] = (_Float16)v.w;
        *(uint2*)(out + 4 * (size_t)i) = p.u;
    }
}

// W f32 [K][N] -> WT f16 [N][K]
__global__ __launch_bounds__(256) void wprep(const float* __restrict__ W,
                                             _Float16* __restrict__ WT,
                                             int K, int N) {
    int idx = blockIdx.x * 256 + threadIdx.x;
    if (idx < K * N) {
        int n = idx / K, k = idx % K;
        WT[idx] = (_Float16)W[k * N + n];
    }
}

// ---------------------------------------------------------------- fused layer
// One block = 64 dst rows. Phase 1: gather-aggregate (MODE 0=max, 1=sum) +
// (1+eps)*self directly into LDS X-tile (f16, swizzled). Phase 2: MFMA
// X @ W (BN=128) + bias + relu, write Y f16. Skips the global round-trip of
// the aggregated tile; MFMA of other blocks overlaps gather latency.
template <int MODE, bool RELU>
__global__ __launch_bounds__(256) void fused_agg_gemm(const _Float16* __restrict__ h,
                                                      const int* __restrict__ rowptr,
                                                      const int* __restrict__ esrc,
                                                      const float* __restrict__ eps,
                                                      int ei,
                                                      const _Float16* __restrict__ WT,
                                                      const float* __restrict__ bias,
                                                      _Float16* __restrict__ Yh) {
    __shared__ _Float16 Xs[64 * 128];    // 16 KB
    __shared__ _Float16 Ws[128 * 128];   // 32 KB
    char* xb = (char*)Xs;
    char* wb = (char*)Ws;

    int t = threadIdx.x;
    int l = t & 63, w = t >> 6;
    int lr = l & 15, lg = l >> 4;
    int rowBase = blockIdx.x * 64;

    // stage W tile: 128 rows x 256B, 4KB per pass (runs before barrier)
#pragma unroll
    for (int p = 0; p < 8; ++p) {
        int idx = p * 4096 + t * 16;
        int row = idx >> 8, byte = idx & 255;
        *(half8*)(wb + row * 256 + (byte ^ ((row & 7) << 4))) =
            *(const half8*)((const char*)WT + idx);
    }

    // ---- phase 1: aggregate. Each 16-lane group owns one node per pass;
    // 4 passes -> wave w fills rows w*16 .. w*16+15 of Xs.
    float sc = 1.f + eps[ei];
    const _Float16 NEUT = (MODE == 0) ? (_Float16)(-65504.0f) : (_Float16)(0.0f);
    half8 neut8 = {NEUT, NEUT, NEUT, NEUT, NEUT, NEUT, NEUT, NEUT};

    for (int sub = 0; sub < 4; ++sub) {
        int rloc = w * 16 + sub * 4 + lg;
        int node = rowBase + rloc;
        half8 ov = {};
        if (node < N_NODES) {
            int beg = rowptr[node], end = rowptr[node + 1];
            int deg = end - beg;
            half8 acc = neut8;
            for (int e = beg; e < end; e += 8) {
                half8 v[8];
#pragma unroll
                for (int j = 0; j < 8; ++j) {
                    int ee = e + j;
                    int s = esrc[ee < end ? ee : end - 1];
                    v[j] = *(const half8*)(h + (size_t)s * FEAT + lr * 8);
                }
#pragma unroll
                for (int j = 0; j < 8; ++j)
                    if (e + j >= end) v[j] = neut8;
                if (MODE == 0) {
                    half8 m01 = h8max(v[0], v[1]), m23 = h8max(v[2], v[3]);
                    half8 m45 = h8max(v[4], v[5]), m67 = h8max(v[6], v[7]);
                    acc = h8max(acc, h8max(h8max(m01, m23), h8max(m45, m67)));
                } else {
                    half8 s01 = v[0] + v[1], s23 = v[2] + v[3];
                    half8 s45 = v[4] + v[5], s67 = v[6] + v[7];
                    acc += (s01 + s23) + (s45 + s67);
                }
            }
            float a[8];
#pragma unroll
            for (int i = 0; i < 8; ++i) a[i] = (float)acc[i];
            if (MODE == 0 && deg == 0) {
#pragma unroll
                for (int i = 0; i < 8; ++i) a[i] = 0.f;
            }
            half8 self = *(const half8*)(h + (size_t)node * FEAT + lr * 8);
#pragma unroll
            for (int i = 0; i < 8; ++i)
                ov[i] = (_Float16)fmaf(sc, (float)self[i], a[i]);
        }
        *(half8*)(xb + rloc * 256 + ((lr * 16) ^ ((rloc & 7) << 4))) = ov;
    }
    __syncthreads();

    // ---- phase 2: MFMA 64x128 tile
    floatx4 acc[8];
#pragma unroll
    for (int ct = 0; ct < 8; ++ct)
#pragma unroll
        for (int r = 0; r < 4; ++r) acc[ct][r] = 0.f;

#pragma unroll
    for (int ks = 0; ks < 4; ++ks) {
        int kbyte = ks * 64 + lg * 16;
        int r = w * 16 + lr;
        half8 a = *(const half8*)(xb + r * 256 + (kbyte ^ ((r & 7) << 4)));
#pragma unroll
        for (int ct = 0; ct < 8; ++ct) {
            int n = ct * 16 + lr;
            half8 b = *(const half8*)(wb + n * 256 + (kbyte ^ ((n & 7) << 4)));
            acc[ct] = __builtin_amdgcn_mfma_f32_16x16x32_f16(a, b, acc[ct], 0, 0, 0);
        }
    }

    float bv[8];
#pragma unroll
    for (int ct = 0; ct < 8; ++ct) bv[ct] = bias[ct * 16 + lr];

    // epilogue: bounce through Xs for coalesced f16 stores
    __syncthreads();
#pragma unroll
    for (int ct = 0; ct < 8; ++ct)
#pragma unroll
        for (int r = 0; r < 4; ++r) {
            int row = w * 16 + lg * 4 + r;
            int col = ct * 16 + lr;
            float v = acc[ct][r] + bv[ct];
            if (RELU) v = fmaxf(v, 0.f);
            *(_Float16*)(xb + row * 256 + ((col * 2) ^ ((row & 7) << 4))) =
                (_Float16)v;
        }
    __syncthreads();
    {
        int row = t >> 2, q = t & 3;
        int grow = rowBase + row;
        if (grow < N_NODES) {
            char* dstp = (char*)(Yh + (size_t)grow * 128) + q * 64;
#pragma unroll
            for (int j = 0; j < 4; ++j) {
                int byte = q * 64 + j * 16;
                half8 v = *(const half8*)(xb + row * 256 + (byte ^ ((row & 7) << 4)));
                *(half8*)(dstp + j * 16) = v;
            }
        }
    }
}

// ---------------------------------------------------------------- aggregation (final layer, D=64 mean + bias -> f32)
template <int MODE, int D, bool OUTF32, bool BIAS>
__global__ __launch_bounds__(256) void agg_kernel(const _Float16* __restrict__ h,
                                                  const int* __restrict__ rowptr,
                                                  const int* __restrict__ esrc,
                                                  const float* __restrict__ eps,
                                                  int ei,
                                                  const float* __restrict__ bias,
                                                  _Float16* __restrict__ outH,
                                                  float* __restrict__ outF) {
    constexpr int LPE = D / 8;
    constexpr int NPW = 64 / LPE;
    int wid = (int)((blockIdx.x * 256 + threadIdx.x) >> 6);
    int l = threadIdx.x & 63;
    int grp = l / LPE, sl = l % LPE;
    int node = wid * NPW + grp;
    if (node >= N_NODES) return;
    int beg = rowptr[node], end = rowptr[node + 1];
    int deg = end - beg;

    const _Float16 NEUT = (MODE == 0) ? (_Float16)(-65504.0f) : (_Float16)(0.0f);
    half8 neut8 = {NEUT, NEUT, NEUT, NEUT, NEUT, NEUT, NEUT, NEUT};
    half8 acc = neut8;

    for (int e = beg; e < end; e += 8) {
        half8 v[8];
#pragma unroll
        for (int j = 0; j < 8; ++j) {
            int ee = e + j;
            int s = esrc[ee < end ? ee : end - 1];
            v[j] = *(const half8*)(h + (size_t)s * D + sl * 8);
        }
#pragma unroll
        for (int j = 0; j < 8; ++j)
            if (e + j >= end) v[j] = neut8;
        if (MODE == 0) {
            half8 m01 = h8max(v[0], v[1]), m23 = h8max(v[2], v[3]);
            half8 m45 = h8max(v[4], v[5]), m67 = h8max(v[6], v[7]);
            acc = h8max(acc, h8max(h8max(m01, m23), h8max(m45, m67)));
        } else {
            half8 s01 = v[0] + v[1], s23 = v[2] + v[3];
            half8 s45 = v[4] + v[5], s67 = v[6] + v[7];
            acc += (s01 + s23) + (s45 + s67);
        }
    }

    float a[8];
#pragma unroll
    for (int i = 0; i < 8; ++i) a[i] = (float)acc[i];
    if (MODE == 0 && deg == 0) {
#pragma unroll
        for (int i = 0; i < 8; ++i) a[i] = 0.f;
    }
    if (MODE == 2) {
        float inv = 1.f / (float)(deg > 0 ? deg : 1);
#pragma unroll
        for (int i = 0; i < 8; ++i) a[i] *= inv;
    }
    float sc = 1.f + eps[ei];
    half8 self = *(const half8*)(h + (size_t)node * D + sl * 8);
    float o[8];
#pragma unroll
    for (int i = 0; i < 8; ++i) o[i] = fmaf(sc, (float)self[i], a[i]);

    if (OUTF32) {
#pragma unroll
        for (int i = 0; i < 8; ++i)
            if (BIAS) o[i] += bias[sl * 8 + i];
        float4* dstp = (float4*)(outF + (size_t)node * D + sl * 8);
        dstp[0] = make_float4(o[0], o[1], o[2], o[3]);
        dstp[1] = make_float4(o[4], o[5], o[6], o[7]);
    } else {
        half8 ov;
#pragma unroll
        for (int i = 0; i < 8; ++i) ov[i] = (_Float16)o[i];
        *(half8*)(outH + (size_t)node * D + sl * 8) = ov;
    }
}

// ---------------------------------------------------------------- MFMA GEMM (layer-3 transform, BN=64)
template <int BN, bool RELU, bool BIAS>
__global__ __launch_bounds__(256) void gemm_mfma(const _Float16* __restrict__ X,
                                                 const _Float16* __restrict__ WT,
                                                 const float* __restrict__ bias,
                                                 _Float16* __restrict__ Yh) {
    __shared__ _Float16 Xs[64 * 128];
    __shared__ _Float16 Ws[BN * 128];
    char* xb = (char*)Xs;
    char* wb = (char*)Ws;

    int t = threadIdx.x;
    int l = t & 63, w = t >> 6;
    int lr = l & 15, lg = l >> 4;
    int rowBase = blockIdx.x * 64;

    {
        int row = t >> 2, q = t & 3;
        int grow = rowBase + row;
        const char* srcp = (const char*)(X + (size_t)grow * 128) + q * 64;
#pragma unroll
        for (int j = 0; j < 4; ++j) {
            int byte = q * 64 + j * 16;
            half8 v = {};
            if (grow < N_NODES) v = *(const half8*)(srcp + j * 16);
            *(half8*)(xb + row * 256 + (byte ^ ((row & 7) << 4))) = v;
        }
    }
    {
#pragma unroll
        for (int p = 0; p < BN / 16; ++p) {
            int idx = p * 4096 + t * 16;
            int row = idx >> 8, byte = idx & 255;
            *(half8*)(wb + row * 256 + (byte ^ ((row & 7) << 4))) =
                *(const half8*)((const char*)WT + idx);
        }
    }
    __syncthreads();

    constexpr int NCT = BN / 16;
    floatx4 acc[NCT];
#pragma unroll
    for (int ct = 0; ct < NCT; ++ct)
#pragma unroll
        for (int r = 0; r < 4; ++r) acc[ct][r] = 0.f;

#pragma unroll
    for (int ks = 0; ks < 4; ++ks) {
        int kbyte = ks * 64 + lg * 16;
        int r = w * 16 + lr;
        half8 a = *(const half8*)(xb + r * 256 + (kbyte ^ ((r & 7) << 4)));
#pragma unroll
        for (int ct = 0; ct < NCT; ++ct) {
            int n = ct * 16 + lr;
            half8 b = *(const half8*)(wb + n * 256 + (kbyte ^ ((n & 7) << 4)));
            acc[ct] = __builtin_amdgcn_mfma_f32_16x16x32_f16(a, b, acc[ct], 0, 0, 0);
        }
    }

    float bv[NCT];
#pragma unroll
    for (int ct = 0; ct < NCT; ++ct) bv[ct] = BIAS ? bias[ct * 16 + lr] : 0.f;

    constexpr int ROWB = BN * 2;
    __syncthreads();
#pragma unroll
    for (int ct = 0; ct < NCT; ++ct)
#pragma unroll
        for (int r = 0; r < 4; ++r) {
            int row = w * 16 + lg * 4 + r;
            int col = ct * 16 + lr;
            float v = acc[ct][r] + bv[ct];
            if (RELU) v = fmaxf(v, 0.f);
            *(_Float16*)(xb + row * ROWB + ((col * 2) ^ ((row & 7) << 4))) =
                (_Float16)v;
        }
    __syncthreads();
    {
        int row = t >> 2, q = t & 3;
        int grow = rowBase + row;
        if (grow < N_NODES) {
            char* dstp = (char*)(Yh + (size_t)grow * BN) + q * (ROWB / 4);
#pragma unroll
            for (int j = 0; j < ROWB / 64; ++j) {
                int byte = q * (ROWB / 4) + j * 16;
                half8 v = *(const half8*)(xb + row * ROWB + (byte ^ ((row & 7) << 4)));
                *(half8*)(dstp + j * 16) = v;
            }
        }
    }
}

// ---------------------------------------------------------------- launch
extern "C" void kernel_launch(void* const* d_in, const int* in_sizes, int n_in,
                              void* d_out, int out_size, void* d_ws, size_t ws_size,
                              hipStream_t stream) {
    const float* feat = (const float*)d_in[0];
    const int*   src  = (const int*)d_in[1];
    const int*   dst  = (const int*)d_in[2];
    const float* W1   = (const float*)d_in[3];
    const float* b1   = (const float*)d_in[4];
    const float* W2a  = (const float*)d_in[5];
    const float* b2a  = (const float*)d_in[6];
    const float* W2b  = (const float*)d_in[7];
    const float* b2b  = (const float*)d_in[8];
    const float* W3   = (const float*)d_in[9];
    const float* b3   = (const float*)d_in[10];
    const float* eps  = (const float*)d_in[11];

    const size_t NH = (size_t)N_NODES * FEAT;
    char* base = (char*)d_ws;
    auto alloc = [&](size_t bytes) {
        char* p = base;
        base += (bytes + 255) & ~(size_t)255;
        return p;
    };
    _Float16* featH = (_Float16*)alloc(NH * 2);
    _Float16* hA    = (_Float16*)alloc(NH * 2);
    _Float16* hB    = (_Float16*)alloc(NH * 2);
    _Float16* WT1   = (_Float16*)alloc(128 * 128 * 2);
    _Float16* WT2a  = (_Float16*)alloc(128 * 128 * 2);
    _Float16* WT2b  = (_Float16*)alloc(128 * 128 * 2);
    _Float16* WT3   = (_Float16*)alloc(128 * 64 * 2);
    uint2* ebuf     = (uint2*)alloc((size_t)NBUCKET * BCAP * 8);
    int* rowptr     = (int*)alloc((N_NODES + 1) * 4);
    int* esrc       = (int*)alloc((size_t)N_EDGES * 4);
    int* gcur       = (int*)alloc(NBUCKET * 4);
    int* bbase      = (int*)alloc(NBUCKET * 4);

    // --- preps
    f32_to_f16_vec<<<2048, 256, 0, stream>>>(feat, featH, (int)(NH / 4));
    wprep<<<64, 256, 0, stream>>>(W1, WT1, 128, 128);
    wprep<<<64, 256, 0, stream>>>(W2a, WT2a, 128, 128);
    wprep<<<64, 256, 0, stream>>>(W2b, WT2b, 128, 128);
    wprep<<<32, 256, 0, stream>>>(W3, WT3, 128, 64);

    // --- bucketed CSR build
    zero_i32<<<(NBUCKET + 255) / 256, 256, 0, stream>>>(gcur, NBUCKET);
    bin_edges<<<(N_EDGES + 4095) / 4096, 512, 0, stream>>>(src, dst, ebuf, gcur);
    scan_buckets<<<1, 512, 0, stream>>>(gcur, bbase, rowptr);
    bucket_csr<<<NBUCKET, 256, 0, stream>>>(ebuf, gcur, bbase, rowptr, esrc);

    const int FUSED_GRID = (N_NODES + 63) / 64;    // 1563
    const int AGG64_GRID = (N_NODES + 31) / 32;    // NPW=8 -> 32 nodes/block
    const int GEMM_GRID  = (N_NODES + 63) / 64;

    // layer 0: max agg + W1 + relu (fused)
    fused_agg_gemm<0, true><<<FUSED_GRID, 256, 0, stream>>>(
        featH, rowptr, esrc, eps, 0, WT1, b1, hA);
    // layer 1: sum agg + W2a + relu (fused)
    fused_agg_gemm<1, true><<<FUSED_GRID, 256, 0, stream>>>(
        hA, rowptr, esrc, eps, 1, WT2a, b2a, hB);
    // layer 2: sum agg + W2b + relu (fused)
    fused_agg_gemm<1, true><<<FUSED_GRID, 256, 0, stream>>>(
        hB, rowptr, esrc, eps, 2, WT2b, b2b, hA);
    // layer 3 (transform-first): p = hA@W3 (f16), then mean-agg(64) + b3 -> f32
    gemm_mfma<64, false, false><<<GEMM_GRID, 256, 0, stream>>>(hA, WT3, nullptr, hB);
    agg_kernel<2, 64, true, true><<<AGG64_GRID, 256, 0, stream>>>(
        hB, rowptr, esrc, eps, 3, b3, nullptr, (float*)d_out);
}